// Round 1
// 965.085 us; speedup vs baseline: 1.0396x; 1.0396x over previous
//
#include <hip/hip_runtime.h>
#include <math.h>

#define N0 8192
#define D 128

typedef __attribute__((ext_vector_type(8))) short short8;
typedef __attribute__((ext_vector_type(4))) float f32x4;

__device__ inline short f2bf(float f) {
    unsigned u = __float_as_uint(f);
    u = u + 0x7fffu + ((u >> 16) & 1u);
    return (short)(u >> 16);
}

// RNE 3-way bf16 split: v ~= h + m + l, residual ~2^-24 relative
__device__ inline void split3(float v, short& h, short& m, short& l) {
    unsigned u = __float_as_uint(v);
    unsigned hs = (u + 0x7fffu + ((u >> 16) & 1u)) >> 16;
    h = (short)hs;
    float rem = v - __uint_as_float(hs << 16);     // exact
    unsigned ur = __float_as_uint(rem);
    unsigned ms = (ur + 0x7fffu + ((ur >> 16) & 1u)) >> 16;
    m = (short)ms;
    float rem2 = rem - __uint_as_float(ms << 16);  // exact
    unsigned u2 = __float_as_uint(rem2);
    l = (short)((u2 + 0x7fffu + ((u2 >> 16) & 1u)) >> 16);
}

// ---------------- score: s[i] = tanh((x[i]·w)/||w||), tanh in fp64 ----------------
__global__ void score_kernel(const float* __restrict__ x, const float* __restrict__ w,
                             float* __restrict__ score, int n) {
    __shared__ float red[128];
    __shared__ float red2[128];
    int row = blockIdx.x;
    int t = threadIdx.x;
    float wv = w[t];
    float xv = x[row * D + t];
    red[t] = xv * wv;
    red2[t] = wv * wv;
    __syncthreads();
    for (int s = 64; s > 0; s >>= 1) {
        if (t < s) { red[t] += red[t + s]; red2[t] += red2[t + s]; }
        __syncthreads();
    }
    if (t == 0) {
        double a = (double)red[0] / sqrt((double)red2[0]);
        score[row] = (float)tanh(a);
    }
}

// ---------------- exact top-k: bitonic sort of (desc score, asc index) keys -------
// Also emits: sperm = selected indices in ASCENDING order, pos[c] = rank of sperm[c]
// in perm (i.e. sperm[c] == perm[pos[c]]), and selg[v] = rank if v selected else -1.
__global__ void topk_sort_kernel(const float* __restrict__ score, int n, int k,
                                 int* __restrict__ perm, float* __restrict__ gate,
                                 int* __restrict__ sperm, int* __restrict__ pos,
                                 int* __restrict__ selg) {
    extern __shared__ unsigned long long keys[];
    int t = threadIdx.x;
    int bs = blockDim.x;
    for (int i = t; i < n; i += bs) {
        unsigned int b = __float_as_uint(score[i]);
        unsigned int ord = (b & 0x80000000u) ? ~b : (b | 0x80000000u);
        unsigned int inv = ~ord;
        keys[i] = ((unsigned long long)inv << 32) | (unsigned int)i;
    }
    __syncthreads();
    for (int len = 2; len <= n; len <<= 1) {
        for (int str = len >> 1; str > 0; str >>= 1) {
            for (int i = t; i < n; i += bs) {
                int j = i ^ str;
                if (j > i) {
                    unsigned long long a = keys[i], c = keys[j];
                    bool up = ((i & len) == 0);
                    if ((a > c) == up) { keys[i] = c; keys[j] = a; }
                }
            }
            __syncthreads();
        }
    }
    // extract perm/gate; stash (idx, rank) pairs in registers before LDS reuse
    int idxs[4], ranks[4];
    int nq = 0;
    for (int i = t; i < k; i += bs) {
        int idx = (int)(keys[i] & 0xffffffffu);
        perm[i] = idx;
        gate[i] = score[idx];
        idxs[nq] = idx; ranks[nq] = i; nq++;
    }
    __syncthreads();
    // reuse LDS: sel = n ints (rank by original position), scanb = bs ints
    int* sel = (int*)keys;
    int* scanb = sel + n;
    for (int i = t; i < n; i += bs) sel[i] = -1;
    __syncthreads();
    for (int q = 0; q < nq; q++) sel[idxs[q]] = ranks[q];
    __syncthreads();
    int per = n / bs;
    int base = t * per;
    int cnt = 0;
    for (int j = 0; j < per; j++) cnt += (sel[base + j] >= 0) ? 1 : 0;
    scanb[t] = cnt;
    __syncthreads();
    for (int s2 = 1; s2 < bs; s2 <<= 1) {
        int v = (t >= s2) ? scanb[t - s2] : 0;
        __syncthreads();
        scanb[t] += v;
        __syncthreads();
    }
    int c = scanb[t] - cnt;  // exclusive prefix
    for (int j = 0; j < per; j++) {
        int v = base + j;
        int r = sel[v];
        selg[v] = r;
        if (r >= 0) { sperm[c] = v; pos[c] = r; c++; }
    }
}

// ---------------- xp[j] = x[perm[j]] * gate[j] ----------------
__global__ void pool_gather_kernel(const float* __restrict__ x, const int* __restrict__ perm,
                                   const float* __restrict__ gate, float* __restrict__ xp, int k) {
    int idx = blockIdx.x * blockDim.x + threadIdx.x;
    if (idx >= k * D) return;
    int j = idx >> 7;
    int d = idx & 127;
    xp[idx] = x[perm[j] * D + d] * gate[j];
}

// ---------------- Hg[r][c] = H[perm[r]][sperm[c]]  (ascending cols -> coalesced) ----
__global__ void h_gather_kernel(const float* __restrict__ H, const int* __restrict__ perm,
                                const int* __restrict__ sperm, float* __restrict__ Hg,
                                int k, int lg) {
    int idx = blockIdx.x * blockDim.x + threadIdx.x;
    int r = idx >> lg;
    int c = idx & (k - 1);
    if (r >= k) return;
    Hg[idx] = H[(size_t)perm[r] * N0 + sperm[c]];
}

// ------- single-plane transpose+convert with optional source row permute -------
// Tt(128 x n) = bf16(T(pos(n) x 128))^T
__global__ void transpose_cvt_kernel(const float* __restrict__ T, const int* __restrict__ pos,
                                     short* __restrict__ Tt, int n) {
    __shared__ float tile[32][33];
    int tx = threadIdx.x & 31, ty = threadIdx.x >> 5;
    int r0 = blockIdx.x * 32, c0 = blockIdx.y * 32;
#pragma unroll
    for (int k = 0; k < 4; k++) {
        int rr = r0 + ty + k * 8;
        int sr = pos ? pos[rr] : rr;
        tile[ty + k * 8][tx] = T[(size_t)sr * 128 + c0 + tx];
    }
    __syncthreads();
#pragma unroll
    for (int k = 0; k < 4; k++)
        Tt[(size_t)(c0 + ty + k * 8) * n + r0 + tx] = f2bf(tile[tx][ty + k * 8]);
}

// ------- split transpose with optional source row permute: 3 bf16 planes -------
__global__ void split_transpose_kernel(const float* __restrict__ T, const int* __restrict__ pos,
                                       short* __restrict__ Th, short* __restrict__ Tm,
                                       short* __restrict__ Tl, int n) {
    __shared__ float tile[32][33];
    int tx = threadIdx.x & 31, ty = threadIdx.x >> 5;
    int r0 = blockIdx.x * 32, c0 = blockIdx.y * 32;
#pragma unroll
    for (int k = 0; k < 4; k++) {
        int rr = r0 + ty + k * 8;
        int sr = pos ? pos[rr] : rr;
        tile[ty + k * 8][tx] = T[(size_t)sr * 128 + c0 + tx];
    }
    __syncthreads();
#pragma unroll
    for (int k = 0; k < 4; k++) {
        float v = tile[tx][ty + k * 8];
        short h, m, l;
        split3(v, h, m, l);
        size_t o = (size_t)(c0 + ty + k * 8) * n + r0 + tx;
        Th[o] = h; Tm[o] = m; Tl[o] = l;
    }
}

// ------- fp32-accurate MFMA gemm via 3-way bf16 split, 6 products -------
__global__ __launch_bounds__(256) void mfma_split6_kernel(
        const float* __restrict__ A, const short* __restrict__ Bh,
        const short* __restrict__ Bm, const short* __restrict__ Bl,
        float* __restrict__ pbuf, int M, int K, int chunk) {
    __shared__ __align__(16) short Ah[64 * 40], Am[64 * 40], Al[64 * 40];
    __shared__ __align__(16) short Bhs[128 * 40], Bms[128 * 40], Bls[128 * 40];
    int tid = threadIdx.x;
    int w = tid >> 6, lane = tid & 63;
    int m16 = lane & 15, kq = lane >> 4;
    int bm = blockIdx.x;
    int kbeg = blockIdx.y * chunk;

    f32x4 acc[8];
#pragma unroll
    for (int i = 0; i < 8; i++) acc[i] = (f32x4){0.f, 0.f, 0.f, 0.f};

    const float* Ab = A + (size_t)bm * 64 * K;
    int arow = tid >> 2, acg = (tid & 3) * 8;

    for (int k0 = kbeg; k0 < kbeg + chunk; k0 += 32) {
        {
            const float* src = Ab + (size_t)arow * K + k0 + acg;
            float4 v0 = *(const float4*)src;
            float4 v1 = *(const float4*)(src + 4);
            float vv[8] = {v0.x, v0.y, v0.z, v0.w, v1.x, v1.y, v1.z, v1.w};
            short8 th, tm, tl;
#pragma unroll
            for (int j = 0; j < 8; j++) { short h, m, l; split3(vv[j], h, m, l); th[j] = h; tm[j] = m; tl[j] = l; }
            *(short8*)&Ah[arow * 40 + acg] = th;
            *(short8*)&Am[arow * 40 + acg] = tm;
            *(short8*)&Al[arow * 40 + acg] = tl;
        }
        for (int l = tid; l < 512; l += 256) {
            int nn = l >> 2, kg = (l & 3) * 8;
            size_t go = (size_t)nn * K + k0 + kg;
            int lo = nn * 40 + kg;
            *(short8*)&Bhs[lo] = *(const short8*)&Bh[go];
            *(short8*)&Bms[lo] = *(const short8*)&Bm[go];
            *(short8*)&Bls[lo] = *(const short8*)&Bl[go];
        }
        __syncthreads();
        int ao = (w * 16 + m16) * 40 + kq * 8;
        short8 a_h = *(short8*)&Ah[ao];
        short8 a_m = *(short8*)&Am[ao];
        short8 a_l = *(short8*)&Al[ao];
#pragma unroll
        for (int nf = 0; nf < 8; nf++) {
            int bo = (nf * 16 + m16) * 40 + kq * 8;
            short8 b_h = *(short8*)&Bhs[bo];
            short8 b_m = *(short8*)&Bms[bo];
            short8 b_l = *(short8*)&Bls[bo];
            acc[nf] = __builtin_amdgcn_mfma_f32_16x16x32_bf16(a_h, b_h, acc[nf], 0, 0, 0);
            acc[nf] = __builtin_amdgcn_mfma_f32_16x16x32_bf16(a_h, b_m, acc[nf], 0, 0, 0);
            acc[nf] = __builtin_amdgcn_mfma_f32_16x16x32_bf16(a_m, b_h, acc[nf], 0, 0, 0);
            acc[nf] = __builtin_amdgcn_mfma_f32_16x16x32_bf16(a_h, b_l, acc[nf], 0, 0, 0);
            acc[nf] = __builtin_amdgcn_mfma_f32_16x16x32_bf16(a_l, b_h, acc[nf], 0, 0, 0);
            acc[nf] = __builtin_amdgcn_mfma_f32_16x16x32_bf16(a_m, b_m, acc[nf], 0, 0, 0);
        }
        __syncthreads();
    }
    float* pb = pbuf + (size_t)blockIdx.y * M * 128;
    int rbase = bm * 64 + w * 16 + kq * 4;
#pragma unroll
    for (int nf = 0; nf < 8; nf++) {
        int col = nf * 16 + m16;
#pragma unroll
        for (int i = 0; i < 4; i++)
            pb[(size_t)(rbase + i) * 128 + col] = acc[nf][i];
    }
}

// ------- bf16 MFMA gemm (1 product): A fp32 M x K (cvt in-kernel), Bt 128 x K bf16 -------
__global__ __launch_bounds__(256) void mfma_gemm1_kernel(
        const float* __restrict__ A, const short* __restrict__ Bt,
        float* __restrict__ pbuf, int M, int K, int chunk) {
    __shared__ __align__(16) short As[64 * 40];
    __shared__ __align__(16) short Bs[128 * 40];
    int tid = threadIdx.x;
    int w = tid >> 6, lane = tid & 63;
    int m16 = lane & 15, kq = lane >> 4;
    int bm = blockIdx.x;
    int kbeg = blockIdx.y * chunk;

    f32x4 acc[8];
#pragma unroll
    for (int i = 0; i < 8; i++) acc[i] = (f32x4){0.f, 0.f, 0.f, 0.f};

    const float* Ab = A + (size_t)bm * 64 * K;
    int arow = tid >> 2, acg = (tid & 3) * 8;

    for (int k0 = kbeg; k0 < kbeg + chunk; k0 += 32) {
        {
            const float* src = Ab + (size_t)arow * K + k0 + acg;
            float4 v0 = *(const float4*)src;
            float4 v1 = *(const float4*)(src + 4);
            short8 t;
            t[0] = f2bf(v0.x); t[1] = f2bf(v0.y); t[2] = f2bf(v0.z); t[3] = f2bf(v0.w);
            t[4] = f2bf(v1.x); t[5] = f2bf(v1.y); t[6] = f2bf(v1.z); t[7] = f2bf(v1.w);
            *(short8*)&As[arow * 40 + acg] = t;
        }
        for (int l = tid; l < 512; l += 256) {
            int nn = l >> 2, kg = (l & 3) * 8;
            *(short8*)&Bs[nn * 40 + kg] = *(const short8*)&Bt[(size_t)nn * K + k0 + kg];
        }
        __syncthreads();
        short8 a = *(short8*)&As[(w * 16 + m16) * 40 + kq * 8];
#pragma unroll
        for (int nf = 0; nf < 8; nf++) {
            short8 b = *(short8*)&Bs[(nf * 16 + m16) * 40 + kq * 8];
            acc[nf] = __builtin_amdgcn_mfma_f32_16x16x32_bf16(a, b, acc[nf], 0, 0, 0);
        }
        __syncthreads();
    }
    float* pb = pbuf + (size_t)blockIdx.y * M * 128;
    int rbase = bm * 64 + w * 16 + kq * 4;
#pragma unroll
    for (int nf = 0; nf < 8; nf++) {
        int col = nf * 16 + m16;
#pragma unroll
        for (int i = 0; i < 4; i++)
            pb[(size_t)(rbase + i) * 128 + col] = acc[nf][i];
    }
}

// ------- reduce split-K partials + optional bias + optional relu -------
__global__ void reduce_kernel(const float* __restrict__ pbuf, int S, size_t MC,
                              const float* __restrict__ bias, int relu,
                              float* __restrict__ dst) {
    size_t idx = ((size_t)blockIdx.x * 256 + threadIdx.x) * 4;
    if (idx >= MC) return;
    float4 v = *(const float4*)(pbuf + idx);
    for (int s = 1; s < S; s++) {
        float4 t = *(const float4*)(pbuf + (size_t)s * MC + idx);
        v.x += t.x; v.y += t.y; v.z += t.z; v.w += t.w;
    }
    if (bias) {
        int c = (int)(idx & 127);
        v.x += bias[c]; v.y += bias[c + 1]; v.z += bias[c + 2]; v.w += bias[c + 3];
    }
    if (relu) {
        v.x = v.x > 0.f ? v.x : 0.f; v.y = v.y > 0.f ? v.y : 0.f;
        v.z = v.z > 0.f ? v.z : 0.f; v.w = v.w > 0.f ? v.w : 0.f;
    }
    *(float4*)(dst + idx) = v;
}

// ---------------- u[v] = res[v] + (selg[v]>=0 ? xc[selg[v]] : 0)  (fused copy+scatter) ----
__global__ void add_scatter_kernel(const float* __restrict__ res, const float* __restrict__ xc,
                                   const int* __restrict__ selg, float* __restrict__ u, int n) {
    int idx = blockIdx.x * blockDim.x + threadIdx.x;
    if (idx >= n * D) return;
    int v = idx >> 7;
    int d = idx & 127;
    int r = selg[v];
    float a = res[idx];
    u[idx] = (r >= 0) ? a + xc[(size_t)r * D + d] : a;
}

extern "C" void kernel_launch(void* const* d_in, const int* in_sizes, int n_in,
                              void* d_out, int out_size, void* d_ws, size_t ws_size,
                              hipStream_t stream) {
    const float* feat = (const float*)d_in[0];
    const float* H    = (const float*)d_in[1];
    const float* p_w[3]  = {(const float*)d_in[2], (const float*)d_in[3], (const float*)d_in[4]};
    const float* Wd[3]   = {(const float*)d_in[5], (const float*)d_in[7], (const float*)d_in[9]};
    const float* bd[3]   = {(const float*)d_in[6], (const float*)d_in[8], (const float*)d_in[10]};
    const float* Wu[3]   = {(const float*)d_in[11], (const float*)d_in[13], (const float*)d_in[15]};
    const float* bu[3]   = {(const float*)d_in[12], (const float*)d_in[14], (const float*)d_in[16]};
    float* out = (float*)d_out;

    // ---- workspace carving ----
    char* wsp = (char*)d_ws;
    size_t off = 0;
    auto alloc = [&](size_t nbytes) { void* p = wsp + off; off += (nbytes + 255) & ~255ull; return p; };
    float* Hg0 = (float*)alloc(4096ull * 4096 * 4);
    float* Hg1 = (float*)alloc(2048ull * 2048 * 4);
    float* Hg2 = (float*)alloc(1024ull * 1024 * 4);
    float* x1  = (float*)alloc(4096ull * D * 4);
    float* x2  = (float*)alloc(2048ull * D * 4);
    float* xp  = (float*)alloc(4096ull * D * 4);   // down: pooled x; up: aliased as ttb (bf16 128x8192)
    float* tbuf = (float*)alloc(8192ull * D * 4);
    float* ubuf = (float*)alloc(8192ull * D * 4);
    float* xc  = (float*)alloc(4096ull * D * 4);
    float* pbuf = (float*)alloc(8ull * 4096 * 128 * 4);   // split-K partial slices (16.8 MB)
    short* Bth = (short*)alloc(128ull * 4096 * 2);
    short* Btm = (short*)alloc(128ull * 4096 * 2);
    short* Btl = (short*)alloc(128ull * 4096 * 2);
    short* Wth = (short*)alloc(128ull * 128 * 2);
    short* Wtm = (short*)alloc(128ull * 128 * 2);
    short* Wtl = (short*)alloc(128ull * 128 * 2);
    float* score = (float*)alloc(8192 * 4);
    float* gate  = (float*)alloc(4096 * 4);
    int* perm0 = (int*)alloc(4096 * 4);
    int* perm1 = (int*)alloc(2048 * 4);
    int* perm2 = (int*)alloc(1024 * 4);
    int* sperm0 = (int*)alloc(4096 * 4);
    int* sperm1 = (int*)alloc(2048 * 4);
    int* sperm2 = (int*)alloc(1024 * 4);
    int* pos0 = (int*)alloc(4096 * 4);
    int* pos1 = (int*)alloc(2048 * 4);
    int* pos2 = (int*)alloc(1024 * 4);
    int* sel0 = (int*)alloc(8192 * 4);
    int* sel1 = (int*)alloc(4096 * 4);
    int* sel2 = (int*)alloc(2048 * 4);
    short* ttb = (short*)xp;

    const int ks[3] = {4096, 2048, 1024};
    const int ns[3] = {8192, 4096, 2048};
    int* perms[3] = {perm0, perm1, perm2};
    int* sperms[3] = {sperm0, sperm1, sperm2};
    int* poss[3] = {pos0, pos1, pos2};
    int* sels[3] = {sel0, sel1, sel2};
    float* Hgs[3] = {Hg0, Hg1, Hg2};
    const float* xin[3] = {feat, x1, x2};
    float* xout[3] = {x1, x2, xc};
    const int dS[3] = {8, 8, 16};

    // ---------------- down path (fp32-accurate split6 MFMA) ----------------
    for (int i = 0; i < 3; i++) {
        int n = ns[i], k = ks[i];
        int lg = (k == 4096) ? 12 : (k == 2048 ? 11 : 10);
        score_kernel<<<n, 128, 0, stream>>>(xin[i], p_w[i], score, n);
        topk_sort_kernel<<<1, 1024, n * 8, stream>>>(score, n, k, perms[i], gate,
                                                     sperms[i], poss[i], sels[i]);
        pool_gather_kernel<<<(k * D) / 256, 256, 0, stream>>>(xin[i], perms[i], gate, xp, k);
        h_gather_kernel<<<(k * k) / 256, 256, 0, stream>>>(H, perms[i], sperms[i], Hgs[i], k, lg);
        // T = xp @ Wd + bd   (split6, K=128, S=2)
        dim3 wg(4, 4);
        split_transpose_kernel<<<wg, 256, 0, stream>>>(Wd[i], nullptr, Wth, Wtm, Wtl, 128);
        dim3 g1(k / 64, 2);
        mfma_split6_kernel<<<g1, 256, 0, stream>>>(xp, Wth, Wtm, Wtl, pbuf, k, 128, 64);
        reduce_kernel<<<(k * 128 / 4 + 255) / 256, 256, 0, stream>>>(pbuf, 2, (size_t)k * 128, bd[i], 0, tbuf);
        // xout = relu(Hg' @ T')  (split6, K=k, S=dS[i]); T' = T[pos] folded into transpose
        dim3 tg(k / 32, 4);
        split_transpose_kernel<<<tg, 256, 0, stream>>>(tbuf, poss[i], Bth, Btm, Btl, k);
        dim3 g2(k / 64, dS[i]);
        mfma_split6_kernel<<<g2, 256, 0, stream>>>(Hgs[i], Bth, Btm, Btl, pbuf, k, k, k / dS[i]);
        reduce_kernel<<<(k * 128 / 4 + 255) / 256, 256, 0, stream>>>(pbuf, dS[i], (size_t)k * 128, nullptr, 1, xout[i]);
    }

    // ---------------- up path (bf16 MFMA) ----------------
    const float* res[3] = {x2, x1, feat};
    const float* graphs[3] = {Hg1, Hg0, H};
    const int* upos[3] = {pos1, pos0, nullptr};   // T-row permute matching graph's column order
    const int* usel[3] = {sel2, sel1, sel0};      // rank array for fused copy+scatter
    const int un[3] = {2048, 4096, 8192};
    const int uS[3] = {8, 8, 4};
    for (int i = 0; i < 3; i++) {
        int n = un[i];
        add_scatter_kernel<<<(n * D) / 256, 256, 0, stream>>>(res[i], xc, usel[i], ubuf, n);
        // T = ubuf @ Wu + bu  (bf16, K=128, S=2)
        dim3 wg(4, 4);
        transpose_cvt_kernel<<<wg, 256, 0, stream>>>(Wu[i], nullptr, Wth, 128);
        dim3 g1(n / 64, 2);
        mfma_gemm1_kernel<<<g1, 256, 0, stream>>>(ubuf, Wth, pbuf, n, 128, 64);
        reduce_kernel<<<(n * 128 / 4 + 255) / 256, 256, 0, stream>>>(pbuf, 2, (size_t)n * 128, bu[i], 0, tbuf);
        // dst = relu(graph' @ T')  (bf16, K=n); T' = T[pos] folded into transpose
        dim3 tg(n / 32, 4);
        transpose_cvt_kernel<<<tg, 256, 0, stream>>>(tbuf, upos[i], ttb, n);
        dim3 g2(n / 64, uS[i]);
        mfma_gemm1_kernel<<<g2, 256, 0, stream>>>(graphs[i], ttb, pbuf, n, n, n / uS[i]);
        float* dst = (i == 2) ? out : xc;
        reduce_kernel<<<(n * 128 / 4 + 255) / 256, 256, 0, stream>>>(pbuf, uS[i], (size_t)n * 128, nullptr, 1, dst);
    }
    (void)in_sizes; (void)n_in; (void)out_size; (void)ws_size;
}

// Round 2
// 804.473 us; speedup vs baseline: 1.2471x; 1.1996x over previous
//
#include <hip/hip_runtime.h>
#include <math.h>

#define N0 8192
#define D 128

typedef __attribute__((ext_vector_type(8))) short short8;
typedef __attribute__((ext_vector_type(4))) float f32x4;

__device__ inline short f2bf(float f) {
    unsigned u = __float_as_uint(f);
    u = u + 0x7fffu + ((u >> 16) & 1u);
    return (short)(u >> 16);
}

// RNE 3-way bf16 split: v ~= h + m + l, residual ~2^-24 relative
__device__ inline void split3(float v, short& h, short& m, short& l) {
    unsigned u = __float_as_uint(v);
    unsigned hs = (u + 0x7fffu + ((u >> 16) & 1u)) >> 16;
    h = (short)hs;
    float rem = v - __uint_as_float(hs << 16);     // exact
    unsigned ur = __float_as_uint(rem);
    unsigned ms = (ur + 0x7fffu + ((ur >> 16) & 1u)) >> 16;
    m = (short)ms;
    float rem2 = rem - __uint_as_float(ms << 16);  // exact
    unsigned u2 = __float_as_uint(rem2);
    l = (short)((u2 + 0x7fffu + ((u2 >> 16) & 1u)) >> 16);
}

// ------- score: s[i] = tanh((x[i]·w)/||w||); also emit sort key + zero rank -------
__global__ void score_kernel(const float* __restrict__ x, const float* __restrict__ w,
                             float* __restrict__ score, unsigned long long* __restrict__ keys,
                             int* __restrict__ rank, int n) {
    __shared__ float red[128];
    __shared__ float red2[128];
    int row = blockIdx.x;
    int t = threadIdx.x;
    float wv = w[t];
    float xv = x[row * D + t];
    red[t] = xv * wv;
    red2[t] = wv * wv;
    __syncthreads();
    for (int s = 64; s > 0; s >>= 1) {
        if (t < s) { red[t] += red[t + s]; red2[t] += red2[t + s]; }
        __syncthreads();
    }
    if (t == 0) {
        double a = (double)red[0] / sqrt((double)red2[0]);
        float sc = (float)tanh(a);
        score[row] = sc;
        unsigned b = __float_as_uint(sc);
        unsigned ord = (b & 0x80000000u) ? ~b : (b | 0x80000000u);
        keys[row] = ((unsigned long long)(~ord) << 32) | (unsigned)row;
        rank[row] = 0;
    }
}

// ------- parallel exact rank: rank[i] = #{j : key[j] < key[i]} (keys unique) -------
// grid (n/1024, n/512); each thread owns 4 i's (stride 256), j-tile of 512 in LDS.
__global__ __launch_bounds__(256) void rank_count_kernel(
        const unsigned long long* __restrict__ keys, int* __restrict__ rank, int n) {
    __shared__ __align__(16) unsigned long long kt[512];
    int tid = threadIdx.x;
    int i0 = blockIdx.x * 1024;
    int j0 = blockIdx.y * 512;
    unsigned long long myk0 = keys[i0 + tid];
    unsigned long long myk1 = keys[i0 + 256 + tid];
    unsigned long long myk2 = keys[i0 + 512 + tid];
    unsigned long long myk3 = keys[i0 + 768 + tid];
    *(ulonglong2*)&kt[2 * tid] = *(const ulonglong2*)&keys[j0 + 2 * tid];
    __syncthreads();
    int c0 = 0, c1 = 0, c2 = 0, c3 = 0;
#pragma unroll 4
    for (int j = 0; j < 256; j++) {
        unsigned long long a = kt[2 * j], b = kt[2 * j + 1];
        c0 += (a < myk0) + (b < myk0);
        c1 += (a < myk1) + (b < myk1);
        c2 += (a < myk2) + (b < myk2);
        c3 += (a < myk3) + (b < myk3);
    }
    atomicAdd(&rank[i0 + tid], c0);
    atomicAdd(&rank[i0 + 256 + tid], c1);
    atomicAdd(&rank[i0 + 512 + tid], c2);
    atomicAdd(&rank[i0 + 768 + tid], c3);
}

// ------- finalize top-k from ranks: perm/gate/selg + compacted sperm/pos -------
// single block, 1024 threads; n/1024 contiguous elements per thread + block scan.
__global__ void topk_finalize_kernel(const float* __restrict__ score, const int* __restrict__ rank,
                                     int n, int k, int* __restrict__ perm, float* __restrict__ gate,
                                     int* __restrict__ sperm, int* __restrict__ pos,
                                     int* __restrict__ selg) {
    __shared__ int scanb[1024];
    int t = threadIdx.x;
    int per = n >> 10;
    int base = t * per;
    int cnt = 0;
#pragma unroll 8
    for (int j = 0; j < 8; j++) {
        if (j < per) {
            int i = base + j;
            int r = rank[i];
            if (r < k) { cnt++; perm[r] = i; gate[r] = score[i]; selg[i] = r; }
            else selg[i] = -1;
        }
    }
    scanb[t] = cnt;
    __syncthreads();
    for (int s = 1; s < 1024; s <<= 1) {
        int v = (t >= s) ? scanb[t - s] : 0;
        __syncthreads();
        scanb[t] += v;
        __syncthreads();
    }
    int c = scanb[t] - cnt;  // exclusive prefix of selected-count
#pragma unroll 8
    for (int j = 0; j < 8; j++) {
        if (j < per) {
            int i = base + j;
            int r = rank[i];
            if (r < k) { sperm[c] = i; pos[c] = r; c++; }
        }
    }
}

// ---------------- xp[j] = x[perm[j]] * gate[j] ----------------
__global__ void pool_gather_kernel(const float* __restrict__ x, const int* __restrict__ perm,
                                   const float* __restrict__ gate, float* __restrict__ xp, int k) {
    int idx = blockIdx.x * blockDim.x + threadIdx.x;
    if (idx >= k * D) return;
    int j = idx >> 7;
    int d = idx & 127;
    xp[idx] = x[perm[j] * D + d] * gate[j];
}

// ---------------- Hg[r][c] = H[perm[r]][sperm[c]]  (ascending cols -> coalesced) ----
__global__ void h_gather_kernel(const float* __restrict__ H, const int* __restrict__ perm,
                                const int* __restrict__ sperm, float* __restrict__ Hg,
                                int k, int lg) {
    int idx = blockIdx.x * blockDim.x + threadIdx.x;
    int r = idx >> lg;
    int c = idx & (k - 1);
    if (r >= k) return;
    Hg[idx] = H[(size_t)perm[r] * N0 + sperm[c]];
}

// ------- single-plane transpose+convert (weights): Tt(128 x n) = bf16(T)^T -------
__global__ void transpose_cvt_kernel(const float* __restrict__ T, short* __restrict__ Tt, int n) {
    __shared__ float tile[32][33];
    int tx = threadIdx.x & 31, ty = threadIdx.x >> 5;
    int r0 = blockIdx.x * 32, c0 = blockIdx.y * 32;
#pragma unroll
    for (int k = 0; k < 4; k++)
        tile[ty + k * 8][tx] = T[(size_t)(r0 + ty + k * 8) * 128 + c0 + tx];
    __syncthreads();
#pragma unroll
    for (int k = 0; k < 4; k++)
        Tt[(size_t)(c0 + ty + k * 8) * n + r0 + tx] = f2bf(tile[tx][ty + k * 8]);
}

// ------- split transpose (weights): 3 bf16 planes (128 x n) from T(n x 128 fp32) -------
__global__ void split_transpose_kernel(const float* __restrict__ T, short* __restrict__ Th,
                                       short* __restrict__ Tm, short* __restrict__ Tl, int n) {
    __shared__ float tile[32][33];
    int tx = threadIdx.x & 31, ty = threadIdx.x >> 5;
    int r0 = blockIdx.x * 32, c0 = blockIdx.y * 32;
#pragma unroll
    for (int k = 0; k < 4; k++)
        tile[ty + k * 8][tx] = T[(size_t)(r0 + ty + k * 8) * 128 + c0 + tx];
    __syncthreads();
#pragma unroll
    for (int k = 0; k < 4; k++) {
        float v = tile[tx][ty + k * 8];
        short h, m, l;
        split3(v, h, m, l);
        size_t o = (size_t)(c0 + ty + k * 8) * n + r0 + tx;
        Th[o] = h; Tm[o] = m; Tl[o] = l;
    }
}

// ------- FUSED: split-K reduce + bias + (pos row-permute) + transpose + split3 -------
__global__ void reduce_split_transpose_kernel(const float* __restrict__ pbuf, int S, int M,
        const float* __restrict__ bias, const int* __restrict__ pos,
        short* __restrict__ Th, short* __restrict__ Tm, short* __restrict__ Tl, int n) {
    __shared__ float tile[32][33];
    int tx = threadIdx.x & 31, ty = threadIdx.x >> 5;
    int r0 = blockIdx.x * 32, c0 = blockIdx.y * 32;
#pragma unroll
    for (int kk = 0; kk < 4; kk++) {
        int rr = r0 + ty + kk * 8;
        int sr = pos ? pos[rr] : rr;
        size_t o = (size_t)sr * 128 + c0 + tx;
        float v = pbuf[o];
        for (int s = 1; s < S; s++) v += pbuf[(size_t)s * M * 128 + o];
        tile[ty + kk * 8][tx] = v + bias[c0 + tx];
    }
    __syncthreads();
#pragma unroll
    for (int kk = 0; kk < 4; kk++) {
        float v = tile[tx][ty + kk * 8];
        short h, m, l;
        split3(v, h, m, l);
        size_t o = (size_t)(c0 + ty + kk * 8) * n + r0 + tx;
        Th[o] = h; Tm[o] = m; Tl[o] = l;
    }
}

// ------- FUSED: split-K reduce + bias + (pos row-permute) + transpose + bf16 cvt -------
__global__ void reduce_transpose_cvt_kernel(const float* __restrict__ pbuf, int S, int M,
        const float* __restrict__ bias, const int* __restrict__ pos,
        short* __restrict__ Tt, int n) {
    __shared__ float tile[32][33];
    int tx = threadIdx.x & 31, ty = threadIdx.x >> 5;
    int r0 = blockIdx.x * 32, c0 = blockIdx.y * 32;
#pragma unroll
    for (int kk = 0; kk < 4; kk++) {
        int rr = r0 + ty + kk * 8;
        int sr = pos ? pos[rr] : rr;
        size_t o = (size_t)sr * 128 + c0 + tx;
        float v = pbuf[o];
        for (int s = 1; s < S; s++) v += pbuf[(size_t)s * M * 128 + o];
        tile[ty + kk * 8][tx] = v + bias[c0 + tx];
    }
    __syncthreads();
#pragma unroll
    for (int kk = 0; kk < 4; kk++)
        Tt[(size_t)(c0 + ty + kk * 8) * n + r0 + tx] = f2bf(tile[tx][ty + kk * 8]);
}

// ------- fp32-accurate MFMA gemm via 3-way bf16 split, 6 products -------
__global__ __launch_bounds__(256) void mfma_split6_kernel(
        const float* __restrict__ A, const short* __restrict__ Bh,
        const short* __restrict__ Bm, const short* __restrict__ Bl,
        float* __restrict__ pbuf, int M, int K, int chunk) {
    __shared__ __align__(16) short Ah[64 * 40], Am[64 * 40], Al[64 * 40];
    __shared__ __align__(16) short Bhs[128 * 40], Bms[128 * 40], Bls[128 * 40];
    int tid = threadIdx.x;
    int w = tid >> 6, lane = tid & 63;
    int m16 = lane & 15, kq = lane >> 4;
    int bm = blockIdx.x;
    int kbeg = blockIdx.y * chunk;

    f32x4 acc[8];
#pragma unroll
    for (int i = 0; i < 8; i++) acc[i] = (f32x4){0.f, 0.f, 0.f, 0.f};

    const float* Ab = A + (size_t)bm * 64 * K;
    int arow = tid >> 2, acg = (tid & 3) * 8;

    for (int k0 = kbeg; k0 < kbeg + chunk; k0 += 32) {
        {
            const float* src = Ab + (size_t)arow * K + k0 + acg;
            float4 v0 = *(const float4*)src;
            float4 v1 = *(const float4*)(src + 4);
            float vv[8] = {v0.x, v0.y, v0.z, v0.w, v1.x, v1.y, v1.z, v1.w};
            short8 th, tm, tl;
#pragma unroll
            for (int j = 0; j < 8; j++) { short h, m, l; split3(vv[j], h, m, l); th[j] = h; tm[j] = m; tl[j] = l; }
            *(short8*)&Ah[arow * 40 + acg] = th;
            *(short8*)&Am[arow * 40 + acg] = tm;
            *(short8*)&Al[arow * 40 + acg] = tl;
        }
        for (int l = tid; l < 512; l += 256) {
            int nn = l >> 2, kg = (l & 3) * 8;
            size_t go = (size_t)nn * K + k0 + kg;
            int lo = nn * 40 + kg;
            *(short8*)&Bhs[lo] = *(const short8*)&Bh[go];
            *(short8*)&Bms[lo] = *(const short8*)&Bm[go];
            *(short8*)&Bls[lo] = *(const short8*)&Bl[go];
        }
        __syncthreads();
        int ao = (w * 16 + m16) * 40 + kq * 8;
        short8 a_h = *(short8*)&Ah[ao];
        short8 a_m = *(short8*)&Am[ao];
        short8 a_l = *(short8*)&Al[ao];
#pragma unroll
        for (int nf = 0; nf < 8; nf++) {
            int bo = (nf * 16 + m16) * 40 + kq * 8;
            short8 b_h = *(short8*)&Bhs[bo];
            short8 b_m = *(short8*)&Bms[bo];
            short8 b_l = *(short8*)&Bls[bo];
            acc[nf] = __builtin_amdgcn_mfma_f32_16x16x32_bf16(a_h, b_h, acc[nf], 0, 0, 0);
            acc[nf] = __builtin_amdgcn_mfma_f32_16x16x32_bf16(a_h, b_m, acc[nf], 0, 0, 0);
            acc[nf] = __builtin_amdgcn_mfma_f32_16x16x32_bf16(a_m, b_h, acc[nf], 0, 0, 0);
            acc[nf] = __builtin_amdgcn_mfma_f32_16x16x32_bf16(a_h, b_l, acc[nf], 0, 0, 0);
            acc[nf] = __builtin_amdgcn_mfma_f32_16x16x32_bf16(a_l, b_h, acc[nf], 0, 0, 0);
            acc[nf] = __builtin_amdgcn_mfma_f32_16x16x32_bf16(a_m, b_m, acc[nf], 0, 0, 0);
        }
        __syncthreads();
    }
    float* pb = pbuf + (size_t)blockIdx.y * M * 128;
    int rbase = bm * 64 + w * 16 + kq * 4;
#pragma unroll
    for (int nf = 0; nf < 8; nf++) {
        int col = nf * 16 + m16;
#pragma unroll
        for (int i = 0; i < 4; i++)
            pb[(size_t)(rbase + i) * 128 + col] = acc[nf][i];
    }
}

// ------- bf16 MFMA gemm (1 product): A fp32 M x K (cvt in-kernel), Bt 128 x K bf16 -------
__global__ __launch_bounds__(256) void mfma_gemm1_kernel(
        const float* __restrict__ A, const short* __restrict__ Bt,
        float* __restrict__ pbuf, int M, int K, int chunk) {
    __shared__ __align__(16) short As[64 * 40];
    __shared__ __align__(16) short Bs[128 * 40];
    int tid = threadIdx.x;
    int w = tid >> 6, lane = tid & 63;
    int m16 = lane & 15, kq = lane >> 4;
    int bm = blockIdx.x;
    int kbeg = blockIdx.y * chunk;

    f32x4 acc[8];
#pragma unroll
    for (int i = 0; i < 8; i++) acc[i] = (f32x4){0.f, 0.f, 0.f, 0.f};

    const float* Ab = A + (size_t)bm * 64 * K;
    int arow = tid >> 2, acg = (tid & 3) * 8;

    for (int k0 = kbeg; k0 < kbeg + chunk; k0 += 32) {
        {
            const float* src = Ab + (size_t)arow * K + k0 + acg;
            float4 v0 = *(const float4*)src;
            float4 v1 = *(const float4*)(src + 4);
            short8 t;
            t[0] = f2bf(v0.x); t[1] = f2bf(v0.y); t[2] = f2bf(v0.z); t[3] = f2bf(v0.w);
            t[4] = f2bf(v1.x); t[5] = f2bf(v1.y); t[6] = f2bf(v1.z); t[7] = f2bf(v1.w);
            *(short8*)&As[arow * 40 + acg] = t;
        }
        for (int l = tid; l < 512; l += 256) {
            int nn = l >> 2, kg = (l & 3) * 8;
            *(short8*)&Bs[nn * 40 + kg] = *(const short8*)&Bt[(size_t)nn * K + k0 + kg];
        }
        __syncthreads();
        short8 a = *(short8*)&As[(w * 16 + m16) * 40 + kq * 8];
#pragma unroll
        for (int nf = 0; nf < 8; nf++) {
            short8 b = *(short8*)&Bs[(nf * 16 + m16) * 40 + kq * 8];
            acc[nf] = __builtin_amdgcn_mfma_f32_16x16x32_bf16(a, b, acc[nf], 0, 0, 0);
        }
        __syncthreads();
    }
    float* pb = pbuf + (size_t)blockIdx.y * M * 128;
    int rbase = bm * 64 + w * 16 + kq * 4;
#pragma unroll
    for (int nf = 0; nf < 8; nf++) {
        int col = nf * 16 + m16;
#pragma unroll
        for (int i = 0; i < 4; i++)
            pb[(size_t)(rbase + i) * 128 + col] = acc[nf][i];
    }
}

// ------- reduce split-K partials + optional bias + optional relu -------
__global__ void reduce_kernel(const float* __restrict__ pbuf, int S, size_t MC,
                              const float* __restrict__ bias, int relu,
                              float* __restrict__ dst) {
    size_t idx = ((size_t)blockIdx.x * 256 + threadIdx.x) * 4;
    if (idx >= MC) return;
    float4 v = *(const float4*)(pbuf + idx);
    for (int s = 1; s < S; s++) {
        float4 t = *(const float4*)(pbuf + (size_t)s * MC + idx);
        v.x += t.x; v.y += t.y; v.z += t.z; v.w += t.w;
    }
    if (bias) {
        int c = (int)(idx & 127);
        v.x += bias[c]; v.y += bias[c + 1]; v.z += bias[c + 2]; v.w += bias[c + 3];
    }
    if (relu) {
        v.x = v.x > 0.f ? v.x : 0.f; v.y = v.y > 0.f ? v.y : 0.f;
        v.z = v.z > 0.f ? v.z : 0.f; v.w = v.w > 0.f ? v.w : 0.f;
    }
    *(float4*)(dst + idx) = v;
}

// ---------------- u[v] = res[v] + (selg[v]>=0 ? xc[selg[v]] : 0)  (fused copy+scatter) ----
__global__ void add_scatter_kernel(const float* __restrict__ res, const float* __restrict__ xc,
                                   const int* __restrict__ selg, float* __restrict__ u, int n) {
    int idx = blockIdx.x * blockDim.x + threadIdx.x;
    if (idx >= n * D) return;
    int v = idx >> 7;
    int d = idx & 127;
    int r = selg[v];
    float a = res[idx];
    u[idx] = (r >= 0) ? a + xc[(size_t)r * D + d] : a;
}

extern "C" void kernel_launch(void* const* d_in, const int* in_sizes, int n_in,
                              void* d_out, int out_size, void* d_ws, size_t ws_size,
                              hipStream_t stream) {
    const float* feat = (const float*)d_in[0];
    const float* H    = (const float*)d_in[1];
    const float* p_w[3]  = {(const float*)d_in[2], (const float*)d_in[3], (const float*)d_in[4]};
    const float* Wd[3]   = {(const float*)d_in[5], (const float*)d_in[7], (const float*)d_in[9]};
    const float* bd[3]   = {(const float*)d_in[6], (const float*)d_in[8], (const float*)d_in[10]};
    const float* Wu[3]   = {(const float*)d_in[11], (const float*)d_in[13], (const float*)d_in[15]};
    const float* bu[3]   = {(const float*)d_in[12], (const float*)d_in[14], (const float*)d_in[16]};
    float* out = (float*)d_out;

    // ---- workspace carving ----
    char* wsp = (char*)d_ws;
    size_t off = 0;
    auto alloc = [&](size_t nbytes) { void* p = wsp + off; off += (nbytes + 255) & ~255ull; return p; };
    float* Hg0 = (float*)alloc(4096ull * 4096 * 4);
    float* Hg1 = (float*)alloc(2048ull * 2048 * 4);
    float* Hg2 = (float*)alloc(1024ull * 1024 * 4);
    float* x1  = (float*)alloc(4096ull * D * 4);
    float* x2  = (float*)alloc(2048ull * D * 4);
    float* xp  = (float*)alloc(4096ull * D * 4);   // down: pooled x; up: aliased as ttb (bf16 128x8192)
    float* tbuf = (float*)alloc(8192ull * D * 4);  // (unused after fusion; kept for layout stability)
    float* ubuf = (float*)alloc(8192ull * D * 4);
    float* xc  = (float*)alloc(4096ull * D * 4);
    float* pbuf = (float*)alloc(8ull * 4096 * 128 * 4);   // split-K partial slices (16.8 MB)
    short* Bth = (short*)alloc(128ull * 4096 * 2);
    short* Btm = (short*)alloc(128ull * 4096 * 2);
    short* Btl = (short*)alloc(128ull * 4096 * 2);
    short* Wth = (short*)alloc(128ull * 128 * 2);
    short* Wtm = (short*)alloc(128ull * 128 * 2);
    short* Wtl = (short*)alloc(128ull * 128 * 2);
    float* score = (float*)alloc(8192 * 4);
    float* gate  = (float*)alloc(4096 * 4);
    unsigned long long* keys = (unsigned long long*)alloc(8192 * 8);
    int* rank = (int*)alloc(8192 * 4);
    int* perm0 = (int*)alloc(4096 * 4);
    int* perm1 = (int*)alloc(2048 * 4);
    int* perm2 = (int*)alloc(1024 * 4);
    int* sperm0 = (int*)alloc(4096 * 4);
    int* sperm1 = (int*)alloc(2048 * 4);
    int* sperm2 = (int*)alloc(1024 * 4);
    int* pos0 = (int*)alloc(4096 * 4);
    int* pos1 = (int*)alloc(2048 * 4);
    int* pos2 = (int*)alloc(1024 * 4);
    int* sel0 = (int*)alloc(8192 * 4);
    int* sel1 = (int*)alloc(4096 * 4);
    int* sel2 = (int*)alloc(2048 * 4);
    short* ttb = (short*)xp;
    (void)tbuf;

    const int ks[3] = {4096, 2048, 1024};
    const int ns[3] = {8192, 4096, 2048};
    int* perms[3] = {perm0, perm1, perm2};
    int* sperms[3] = {sperm0, sperm1, sperm2};
    int* poss[3] = {pos0, pos1, pos2};
    int* sels[3] = {sel0, sel1, sel2};
    float* Hgs[3] = {Hg0, Hg1, Hg2};
    const float* xin[3] = {feat, x1, x2};
    float* xout[3] = {x1, x2, xc};
    const int dS[3] = {8, 8, 16};

    // ---------------- down path (fp32-accurate split6 MFMA) ----------------
    for (int i = 0; i < 3; i++) {
        int n = ns[i], k = ks[i];
        int lg = (k == 4096) ? 12 : (k == 2048 ? 11 : 10);
        score_kernel<<<n, 128, 0, stream>>>(xin[i], p_w[i], score, keys, rank, n);
        dim3 rg(n / 1024, n / 512);
        rank_count_kernel<<<rg, 256, 0, stream>>>(keys, rank, n);
        topk_finalize_kernel<<<1, 1024, 0, stream>>>(score, rank, n, k, perms[i], gate,
                                                     sperms[i], poss[i], sels[i]);
        pool_gather_kernel<<<(k * D) / 256, 256, 0, stream>>>(xin[i], perms[i], gate, xp, k);
        h_gather_kernel<<<(k * k) / 256, 256, 0, stream>>>(H, perms[i], sperms[i], Hgs[i], k, lg);
        // T = xp @ Wd + bd   (split6, K=128, S=2)
        dim3 wg(4, 4);
        split_transpose_kernel<<<wg, 256, 0, stream>>>(Wd[i], Wth, Wtm, Wtl, 128);
        dim3 g1(k / 64, 2);
        mfma_split6_kernel<<<g1, 256, 0, stream>>>(xp, Wth, Wtm, Wtl, pbuf, k, 128, 64);
        // fused: reduce(S=2)+bias+pos-permute+transpose+split3 -> B planes
        dim3 tg(k / 32, 4);
        reduce_split_transpose_kernel<<<tg, 256, 0, stream>>>(pbuf, 2, k, bd[i], poss[i],
                                                              Bth, Btm, Btl, k);
        // xout = relu(Hg' @ T')  (split6, K=k, S=dS[i])
        dim3 g2(k / 64, dS[i]);
        mfma_split6_kernel<<<g2, 256, 0, stream>>>(Hgs[i], Bth, Btm, Btl, pbuf, k, k, k / dS[i]);
        reduce_kernel<<<(k * 128 / 4 + 255) / 256, 256, 0, stream>>>(pbuf, dS[i], (size_t)k * 128, nullptr, 1, xout[i]);
    }

    // ---------------- up path (bf16 MFMA) ----------------
    const float* res[3] = {x2, x1, feat};
    const float* graphs[3] = {Hg1, Hg0, H};
    const int* upos[3] = {pos1, pos0, nullptr};   // T-row permute matching graph's column order
    const int* usel[3] = {sel2, sel1, sel0};      // rank array for fused copy+scatter
    const int un[3] = {2048, 4096, 8192};
    const int uS[3] = {8, 8, 4};
    for (int i = 0; i < 3; i++) {
        int n = un[i];
        add_scatter_kernel<<<(n * D) / 256, 256, 0, stream>>>(res[i], xc, usel[i], ubuf, n);
        // T = ubuf @ Wu + bu  (bf16, K=128, S=2)
        dim3 wg(4, 4);
        transpose_cvt_kernel<<<wg, 256, 0, stream>>>(Wu[i], Wth, 128);
        dim3 g1(n / 64, 2);
        mfma_gemm1_kernel<<<g1, 256, 0, stream>>>(ubuf, Wth, pbuf, n, 128, 64);
        // fused: reduce(S=2)+bias+pos-permute+transpose+cvt -> ttb
        dim3 tg(n / 32, 4);
        reduce_transpose_cvt_kernel<<<tg, 256, 0, stream>>>(pbuf, 2, n, bu[i], upos[i], ttb, n);
        // dst = relu(graph' @ T')  (bf16, K=n)
        dim3 g2(n / 64, uS[i]);
        mfma_gemm1_kernel<<<g2, 256, 0, stream>>>(graphs[i], ttb, pbuf, n, n, n / uS[i]);
        float* dst = (i == 2) ? out : xc;
        reduce_kernel<<<(n * 128 / 4 + 255) / 256, 256, 0, stream>>>(pbuf, uS[i], (size_t)n * 128, nullptr, 1, dst);
    }
    (void)in_sizes; (void)n_in; (void)out_size; (void)ws_size;
}

// Round 3
// 775.405 us; speedup vs baseline: 1.2939x; 1.0375x over previous
//
#include <hip/hip_runtime.h>
#include <math.h>

#define N0 8192
#define D 128

typedef __attribute__((ext_vector_type(8))) short short8;
typedef __attribute__((ext_vector_type(4))) float f32x4;

__device__ inline short f2bf(float f) {
    unsigned u = __float_as_uint(f);
    u = u + 0x7fffu + ((u >> 16) & 1u);
    return (short)(u >> 16);
}

// RNE 3-way bf16 split: v ~= h + m + l, residual ~2^-24 relative
__device__ inline void split3(float v, short& h, short& m, short& l) {
    unsigned u = __float_as_uint(v);
    unsigned hs = (u + 0x7fffu + ((u >> 16) & 1u)) >> 16;
    h = (short)hs;
    float rem = v - __uint_as_float(hs << 16);     // exact
    unsigned ur = __float_as_uint(rem);
    unsigned ms = (ur + 0x7fffu + ((ur >> 16) & 1u)) >> 16;
    m = (short)ms;
    float rem2 = rem - __uint_as_float(ms << 16);  // exact
    unsigned u2 = __float_as_uint(rem2);
    l = (short)((u2 + 0x7fffu + ((u2 >> 16) & 1u)) >> 16);
}

// ------- score (level 0 only): s[i] = tanh((x[i]·w)/||w||); emits key + rank=0 -------
__global__ void score_kernel(const float* __restrict__ x, const float* __restrict__ w,
                             float* __restrict__ score, unsigned long long* __restrict__ keys,
                             int* __restrict__ rank, int n) {
    __shared__ float red[128];
    __shared__ float red2[128];
    int row = blockIdx.x;
    int t = threadIdx.x;
    float wv = w[t];
    float xv = x[row * D + t];
    red[t] = xv * wv;
    red2[t] = wv * wv;
    __syncthreads();
    for (int s = 64; s > 0; s >>= 1) {
        if (t < s) { red[t] += red[t + s]; red2[t] += red2[t + s]; }
        __syncthreads();
    }
    if (t == 0) {
        double a = (double)red[0] / sqrt((double)red2[0]);
        float sc = (float)tanh(a);
        score[row] = sc;
        unsigned b = __float_as_uint(sc);
        unsigned ord = (b & 0x80000000u) ? ~b : (b | 0x80000000u);
        keys[row] = ((unsigned long long)(~ord) << 32) | (unsigned)row;
        rank[row] = 0;
    }
}

// ------- parallel exact rank: rank[i] = #{j : key[j] < key[i]} (keys unique) -------
__global__ __launch_bounds__(256) void rank_count_kernel(
        const unsigned long long* __restrict__ keys, int* __restrict__ rank, int n) {
    __shared__ __align__(16) unsigned long long kt[512];
    int tid = threadIdx.x;
    int i0 = blockIdx.x * 1024;
    int j0 = blockIdx.y * 512;
    unsigned long long myk0 = keys[i0 + tid];
    unsigned long long myk1 = keys[i0 + 256 + tid];
    unsigned long long myk2 = keys[i0 + 512 + tid];
    unsigned long long myk3 = keys[i0 + 768 + tid];
    *(ulonglong2*)&kt[2 * tid] = *(const ulonglong2*)&keys[j0 + 2 * tid];
    __syncthreads();
    int c0 = 0, c1 = 0, c2 = 0, c3 = 0;
#pragma unroll 4
    for (int j = 0; j < 256; j++) {
        unsigned long long a = kt[2 * j], b = kt[2 * j + 1];
        c0 += (a < myk0) + (b < myk0);
        c1 += (a < myk1) + (b < myk1);
        c2 += (a < myk2) + (b < myk2);
        c3 += (a < myk3) + (b < myk3);
    }
    atomicAdd(&rank[i0 + tid], c0);
    atomicAdd(&rank[i0 + 256 + tid], c1);
    atomicAdd(&rank[i0 + 512 + tid], c2);
    atomicAdd(&rank[i0 + 768 + tid], c3);
}

// ------- finalize top-k from ranks: perm/gate/selg + compacted sperm/pos -------
__global__ void topk_finalize_kernel(const float* __restrict__ score, const int* __restrict__ rank,
                                     int n, int k, int* __restrict__ perm, float* __restrict__ gate,
                                     int* __restrict__ sperm, int* __restrict__ pos,
                                     int* __restrict__ selg) {
    __shared__ int scanb[1024];
    int t = threadIdx.x;
    int per = n >> 10;
    int base = t * per;
    int cnt = 0;
#pragma unroll 8
    for (int j = 0; j < 8; j++) {
        if (j < per) {
            int i = base + j;
            int r = rank[i];
            if (r < k) { cnt++; perm[r] = i; gate[r] = score[i]; selg[i] = r; }
            else selg[i] = -1;
        }
    }
    scanb[t] = cnt;
    __syncthreads();
    for (int s = 1; s < 1024; s <<= 1) {
        int v = (t >= s) ? scanb[t - s] : 0;
        __syncthreads();
        scanb[t] += v;
        __syncthreads();
    }
    int c = scanb[t] - cnt;  // exclusive prefix of selected-count
#pragma unroll 8
    for (int j = 0; j < 8; j++) {
        if (j < per) {
            int i = base + j;
            int r = rank[i];
            if (r < k) { sperm[c] = i; pos[c] = r; c++; }
        }
    }
}

// ---------------- Hg[r][c] = H[perm[r]][sperm[c]]  (ascending cols -> coalesced) ----
__global__ void h_gather_kernel(const float* __restrict__ H, const int* __restrict__ perm,
                                const int* __restrict__ sperm, float* __restrict__ Hg,
                                int k, int lg) {
    int idx = blockIdx.x * blockDim.x + threadIdx.x;
    int r = idx >> lg;
    int c = idx & (k - 1);
    if (r >= k) return;
    Hg[idx] = H[(size_t)perm[r] * N0 + sperm[c]];
}

// ------- one-shot weight prep: z<3 split-transpose Wd[z]; z>=3 cvt-transpose Wu[z-3] -----
__global__ void weight_prep_kernel(const float* __restrict__ W0, const float* __restrict__ W1,
                                   const float* __restrict__ W2, const float* __restrict__ W3,
                                   const float* __restrict__ W4, const float* __restrict__ W5,
                                   short* __restrict__ Wth, short* __restrict__ Wtm,
                                   short* __restrict__ Wtl, short* __restrict__ Wut) {
    __shared__ float tile[32][33];
    const float* srcs[6] = {W0, W1, W2, W3, W4, W5};
    int z = blockIdx.z;
    const float* T = srcs[z];
    int tx = threadIdx.x & 31, ty = threadIdx.x >> 5;
    int r0 = blockIdx.x * 32, c0 = blockIdx.y * 32;
#pragma unroll
    for (int kk = 0; kk < 4; kk++)
        tile[ty + kk * 8][tx] = T[(r0 + ty + kk * 8) * 128 + c0 + tx];
    __syncthreads();
    if (z < 3) {
        short* th = Wth + z * 16384; short* tm = Wtm + z * 16384; short* tl = Wtl + z * 16384;
#pragma unroll
        for (int kk = 0; kk < 4; kk++) {
            float v = tile[tx][ty + kk * 8];
            short h, m, l;
            split3(v, h, m, l);
            int o = (c0 + ty + kk * 8) * 128 + r0 + tx;
            th[o] = h; tm[o] = m; tl[o] = l;
        }
    } else {
        short* tt = Wut + (z - 3) * 16384;
#pragma unroll
        for (int kk = 0; kk < 4; kk++)
            tt[(c0 + ty + kk * 8) * 128 + r0 + tx] = f2bf(tile[tx][ty + kk * 8]);
    }
}

// ------- FUSED: split-K reduce + bias + (pos row-permute) + transpose + split3 -------
__global__ void reduce_split_transpose_kernel(const float* __restrict__ pbuf, int S, int M,
        const float* __restrict__ bias, const int* __restrict__ pos,
        short* __restrict__ Th, short* __restrict__ Tm, short* __restrict__ Tl, int n) {
    __shared__ float tile[32][33];
    int tx = threadIdx.x & 31, ty = threadIdx.x >> 5;
    int r0 = blockIdx.x * 32, c0 = blockIdx.y * 32;
#pragma unroll
    for (int kk = 0; kk < 4; kk++) {
        int rr = r0 + ty + kk * 8;
        int sr = pos ? pos[rr] : rr;
        size_t o = (size_t)sr * 128 + c0 + tx;
        float v = pbuf[o];
        for (int s = 1; s < S; s++) v += pbuf[(size_t)s * M * 128 + o];
        tile[ty + kk * 8][tx] = v + bias[c0 + tx];
    }
    __syncthreads();
#pragma unroll
    for (int kk = 0; kk < 4; kk++) {
        float v = tile[tx][ty + kk * 8];
        short h, m, l;
        split3(v, h, m, l);
        size_t o = (size_t)(c0 + ty + kk * 8) * n + r0 + tx;
        Th[o] = h; Tm[o] = m; Tl[o] = l;
    }
}

// ------- FUSED: split-K reduce + bias + (pos row-permute) + transpose + bf16 cvt -------
__global__ void reduce_transpose_cvt_kernel(const float* __restrict__ pbuf, int S, int M,
        const float* __restrict__ bias, const int* __restrict__ pos,
        short* __restrict__ Tt, int n) {
    __shared__ float tile[32][33];
    int tx = threadIdx.x & 31, ty = threadIdx.x >> 5;
    int r0 = blockIdx.x * 32, c0 = blockIdx.y * 32;
#pragma unroll
    for (int kk = 0; kk < 4; kk++) {
        int rr = r0 + ty + kk * 8;
        int sr = pos ? pos[rr] : rr;
        size_t o = (size_t)sr * 128 + c0 + tx;
        float v = pbuf[o];
        for (int s = 1; s < S; s++) v += pbuf[(size_t)s * M * 128 + o];
        tile[ty + kk * 8][tx] = v + bias[c0 + tx];
    }
    __syncthreads();
#pragma unroll
    for (int kk = 0; kk < 4; kk++)
        Tt[(size_t)(c0 + ty + kk * 8) * n + r0 + tx] = f2bf(tile[tx][ty + kk * 8]);
}

// ------- fp32-accurate MFMA gemm via 3-way bf16 split, 6 products (generic A) -------
__global__ __launch_bounds__(256) void mfma_split6_kernel(
        const float* __restrict__ A, const short* __restrict__ Bh,
        const short* __restrict__ Bm, const short* __restrict__ Bl,
        float* __restrict__ pbuf, int M, int K, int chunk) {
    __shared__ __align__(16) short Ah[64 * 40], Am[64 * 40], Al[64 * 40];
    __shared__ __align__(16) short Bhs[128 * 40], Bms[128 * 40], Bls[128 * 40];
    int tid = threadIdx.x;
    int w = tid >> 6, lane = tid & 63;
    int m16 = lane & 15, kq = lane >> 4;
    int bm = blockIdx.x;
    int kbeg = blockIdx.y * chunk;

    f32x4 acc[8];
#pragma unroll
    for (int i = 0; i < 8; i++) acc[i] = (f32x4){0.f, 0.f, 0.f, 0.f};

    const float* Ab = A + (size_t)bm * 64 * K;
    int arow = tid >> 2, acg = (tid & 3) * 8;

    for (int k0 = kbeg; k0 < kbeg + chunk; k0 += 32) {
        {
            const float* src = Ab + (size_t)arow * K + k0 + acg;
            float4 v0 = *(const float4*)src;
            float4 v1 = *(const float4*)(src + 4);
            float vv[8] = {v0.x, v0.y, v0.z, v0.w, v1.x, v1.y, v1.z, v1.w};
            short8 th, tm, tl;
#pragma unroll
            for (int j = 0; j < 8; j++) { short h, m, l; split3(vv[j], h, m, l); th[j] = h; tm[j] = m; tl[j] = l; }
            *(short8*)&Ah[arow * 40 + acg] = th;
            *(short8*)&Am[arow * 40 + acg] = tm;
            *(short8*)&Al[arow * 40 + acg] = tl;
        }
        for (int l = tid; l < 512; l += 256) {
            int nn = l >> 2, kg = (l & 3) * 8;
            size_t go = (size_t)nn * K + k0 + kg;
            int lo = nn * 40 + kg;
            *(short8*)&Bhs[lo] = *(const short8*)&Bh[go];
            *(short8*)&Bms[lo] = *(const short8*)&Bm[go];
            *(short8*)&Bls[lo] = *(const short8*)&Bl[go];
        }
        __syncthreads();
        int ao = (w * 16 + m16) * 40 + kq * 8;
        short8 a_h = *(short8*)&Ah[ao];
        short8 a_m = *(short8*)&Am[ao];
        short8 a_l = *(short8*)&Al[ao];
#pragma unroll
        for (int nf = 0; nf < 8; nf++) {
            int bo = (nf * 16 + m16) * 40 + kq * 8;
            short8 b_h = *(short8*)&Bhs[bo];
            short8 b_m = *(short8*)&Bms[bo];
            short8 b_l = *(short8*)&Bls[bo];
            acc[nf] = __builtin_amdgcn_mfma_f32_16x16x32_bf16(a_h, b_h, acc[nf], 0, 0, 0);
            acc[nf] = __builtin_amdgcn_mfma_f32_16x16x32_bf16(a_h, b_m, acc[nf], 0, 0, 0);
            acc[nf] = __builtin_amdgcn_mfma_f32_16x16x32_bf16(a_m, b_h, acc[nf], 0, 0, 0);
            acc[nf] = __builtin_amdgcn_mfma_f32_16x16x32_bf16(a_h, b_l, acc[nf], 0, 0, 0);
            acc[nf] = __builtin_amdgcn_mfma_f32_16x16x32_bf16(a_l, b_h, acc[nf], 0, 0, 0);
            acc[nf] = __builtin_amdgcn_mfma_f32_16x16x32_bf16(a_m, b_m, acc[nf], 0, 0, 0);
        }
        __syncthreads();
    }
    float* pb = pbuf + (size_t)blockIdx.y * M * 128;
    int rbase = bm * 64 + w * 16 + kq * 4;
#pragma unroll
    for (int nf = 0; nf < 8; nf++) {
        int col = nf * 16 + m16;
#pragma unroll
        for (int i = 0; i < 4; i++)
            pb[(size_t)(rbase + i) * 128 + col] = acc[nf][i];
    }
}

// ------- split6 GEMM with FUSED pool-gather A: A[j] = x[perm[j]] * gate[j], K=128 -------
__global__ __launch_bounds__(256) void mfma_split6_pool_kernel(
        const float* __restrict__ x, const int* __restrict__ perm, const float* __restrict__ gate,
        const short* __restrict__ Bh, const short* __restrict__ Bm, const short* __restrict__ Bl,
        float* __restrict__ pbuf, int M, int K, int chunk) {
    __shared__ __align__(16) short Ah[64 * 40], Am[64 * 40], Al[64 * 40];
    __shared__ __align__(16) short Bhs[128 * 40], Bms[128 * 40], Bls[128 * 40];
    int tid = threadIdx.x;
    int w = tid >> 6, lane = tid & 63;
    int m16 = lane & 15, kq = lane >> 4;
    int bm = blockIdx.x;
    int kbeg = blockIdx.y * chunk;

    f32x4 acc[8];
#pragma unroll
    for (int i = 0; i < 8; i++) acc[i] = (f32x4){0.f, 0.f, 0.f, 0.f};

    int arow = tid >> 2, acg = (tid & 3) * 8;
    int grow = bm * 64 + arow;
    int prow = perm[grow];
    float g = gate[grow];

    for (int k0 = kbeg; k0 < kbeg + chunk; k0 += 32) {
        {
            const float* src = x + (size_t)prow * K + k0 + acg;
            float4 v0 = *(const float4*)src;
            float4 v1 = *(const float4*)(src + 4);
            float vv[8] = {v0.x * g, v0.y * g, v0.z * g, v0.w * g,
                           v1.x * g, v1.y * g, v1.z * g, v1.w * g};
            short8 th, tm, tl;
#pragma unroll
            for (int j = 0; j < 8; j++) { short h, m, l; split3(vv[j], h, m, l); th[j] = h; tm[j] = m; tl[j] = l; }
            *(short8*)&Ah[arow * 40 + acg] = th;
            *(short8*)&Am[arow * 40 + acg] = tm;
            *(short8*)&Al[arow * 40 + acg] = tl;
        }
        for (int l = tid; l < 512; l += 256) {
            int nn = l >> 2, kg = (l & 3) * 8;
            size_t go = (size_t)nn * K + k0 + kg;
            int lo = nn * 40 + kg;
            *(short8*)&Bhs[lo] = *(const short8*)&Bh[go];
            *(short8*)&Bms[lo] = *(const short8*)&Bm[go];
            *(short8*)&Bls[lo] = *(const short8*)&Bl[go];
        }
        __syncthreads();
        int ao = (w * 16 + m16) * 40 + kq * 8;
        short8 a_h = *(short8*)&Ah[ao];
        short8 a_m = *(short8*)&Am[ao];
        short8 a_l = *(short8*)&Al[ao];
#pragma unroll
        for (int nf = 0; nf < 8; nf++) {
            int bo = (nf * 16 + m16) * 40 + kq * 8;
            short8 b_h = *(short8*)&Bhs[bo];
            short8 b_m = *(short8*)&Bms[bo];
            short8 b_l = *(short8*)&Bls[bo];
            acc[nf] = __builtin_amdgcn_mfma_f32_16x16x32_bf16(a_h, b_h, acc[nf], 0, 0, 0);
            acc[nf] = __builtin_amdgcn_mfma_f32_16x16x32_bf16(a_h, b_m, acc[nf], 0, 0, 0);
            acc[nf] = __builtin_amdgcn_mfma_f32_16x16x32_bf16(a_m, b_h, acc[nf], 0, 0, 0);
            acc[nf] = __builtin_amdgcn_mfma_f32_16x16x32_bf16(a_h, b_l, acc[nf], 0, 0, 0);
            acc[nf] = __builtin_amdgcn_mfma_f32_16x16x32_bf16(a_l, b_h, acc[nf], 0, 0, 0);
            acc[nf] = __builtin_amdgcn_mfma_f32_16x16x32_bf16(a_m, b_m, acc[nf], 0, 0, 0);
        }
        __syncthreads();
    }
    float* pb = pbuf + (size_t)blockIdx.y * M * 128;
    int rbase = bm * 64 + w * 16 + kq * 4;
#pragma unroll
    for (int nf = 0; nf < 8; nf++) {
        int col = nf * 16 + m16;
#pragma unroll
        for (int i = 0; i < 4; i++)
            pb[(size_t)(rbase + i) * 128 + col] = acc[nf][i];
    }
}

// ------- bf16 MFMA gemm (1 product, generic A): A fp32 M x K, Bt 128 x K bf16 -------
__global__ __launch_bounds__(256) void mfma_gemm1_kernel(
        const float* __restrict__ A, const short* __restrict__ Bt,
        float* __restrict__ pbuf, int M, int K, int chunk) {
    __shared__ __align__(16) short As[64 * 40];
    __shared__ __align__(16) short Bs[128 * 40];
    int tid = threadIdx.x;
    int w = tid >> 6, lane = tid & 63;
    int m16 = lane & 15, kq = lane >> 4;
    int bm = blockIdx.x;
    int kbeg = blockIdx.y * chunk;

    f32x4 acc[8];
#pragma unroll
    for (int i = 0; i < 8; i++) acc[i] = (f32x4){0.f, 0.f, 0.f, 0.f};

    const float* Ab = A + (size_t)bm * 64 * K;
    int arow = tid >> 2, acg = (tid & 3) * 8;

    for (int k0 = kbeg; k0 < kbeg + chunk; k0 += 32) {
        {
            const float* src = Ab + (size_t)arow * K + k0 + acg;
            float4 v0 = *(const float4*)src;
            float4 v1 = *(const float4*)(src + 4);
            short8 t;
            t[0] = f2bf(v0.x); t[1] = f2bf(v0.y); t[2] = f2bf(v0.z); t[3] = f2bf(v0.w);
            t[4] = f2bf(v1.x); t[5] = f2bf(v1.y); t[6] = f2bf(v1.z); t[7] = f2bf(v1.w);
            *(short8*)&As[arow * 40 + acg] = t;
        }
        for (int l = tid; l < 512; l += 256) {
            int nn = l >> 2, kg = (l & 3) * 8;
            *(short8*)&Bs[nn * 40 + kg] = *(const short8*)&Bt[(size_t)nn * K + k0 + kg];
        }
        __syncthreads();
        short8 a = *(short8*)&As[(w * 16 + m16) * 40 + kq * 8];
#pragma unroll
        for (int nf = 0; nf < 8; nf++) {
            short8 b = *(short8*)&Bs[(nf * 16 + m16) * 40 + kq * 8];
            acc[nf] = __builtin_amdgcn_mfma_f32_16x16x32_bf16(a, b, acc[nf], 0, 0, 0);
        }
        __syncthreads();
    }
    float* pb = pbuf + (size_t)blockIdx.y * M * 128;
    int rbase = bm * 64 + w * 16 + kq * 4;
#pragma unroll
    for (int nf = 0; nf < 8; nf++) {
        int col = nf * 16 + m16;
#pragma unroll
        for (int i = 0; i < 4; i++)
            pb[(size_t)(rbase + i) * 128 + col] = acc[nf][i];
    }
}

// ------- bf16 gemm with FUSED residual+scatter A: A[v]=res[v]+(selg[v]>=0?xc[selg[v]]:0) ----
__global__ __launch_bounds__(256) void mfma_gemm1_add_kernel(
        const float* __restrict__ res, const float* __restrict__ xc, const int* __restrict__ selg,
        const short* __restrict__ Bt, float* __restrict__ pbuf, int M, int K, int chunk) {
    __shared__ __align__(16) short As[64 * 40];
    __shared__ __align__(16) short Bs[128 * 40];
    int tid = threadIdx.x;
    int w = tid >> 6, lane = tid & 63;
    int m16 = lane & 15, kq = lane >> 4;
    int bm = blockIdx.x;
    int kbeg = blockIdx.y * chunk;

    f32x4 acc[8];
#pragma unroll
    for (int i = 0; i < 8; i++) acc[i] = (f32x4){0.f, 0.f, 0.f, 0.f};

    int arow = tid >> 2, acg = (tid & 3) * 8;
    int grow = bm * 64 + arow;
    int r = selg[grow];

    for (int k0 = kbeg; k0 < kbeg + chunk; k0 += 32) {
        {
            const float* s1 = res + (size_t)grow * K + k0 + acg;
            float4 v0 = *(const float4*)s1;
            float4 v1 = *(const float4*)(s1 + 4);
            if (r >= 0) {
                const float* s2 = xc + (size_t)r * K + k0 + acg;
                float4 u0 = *(const float4*)s2;
                float4 u1 = *(const float4*)(s2 + 4);
                v0.x += u0.x; v0.y += u0.y; v0.z += u0.z; v0.w += u0.w;
                v1.x += u1.x; v1.y += u1.y; v1.z += u1.z; v1.w += u1.w;
            }
            short8 t;
            t[0] = f2bf(v0.x); t[1] = f2bf(v0.y); t[2] = f2bf(v0.z); t[3] = f2bf(v0.w);
            t[4] = f2bf(v1.x); t[5] = f2bf(v1.y); t[6] = f2bf(v1.z); t[7] = f2bf(v1.w);
            *(short8*)&As[arow * 40 + acg] = t;
        }
        for (int l = tid; l < 512; l += 256) {
            int nn = l >> 2, kg = (l & 3) * 8;
            *(short8*)&Bs[nn * 40 + kg] = *(const short8*)&Bt[(size_t)nn * K + k0 + kg];
        }
        __syncthreads();
        short8 a = *(short8*)&As[(w * 16 + m16) * 40 + kq * 8];
#pragma unroll
        for (int nf = 0; nf < 8; nf++) {
            short8 b = *(short8*)&Bs[(nf * 16 + m16) * 40 + kq * 8];
            acc[nf] = __builtin_amdgcn_mfma_f32_16x16x32_bf16(a, b, acc[nf], 0, 0, 0);
        }
        __syncthreads();
    }
    float* pb = pbuf + (size_t)blockIdx.y * M * 128;
    int rbase = bm * 64 + w * 16 + kq * 4;
#pragma unroll
    for (int nf = 0; nf < 8; nf++) {
        int col = nf * 16 + m16;
#pragma unroll
        for (int i = 0; i < 4; i++)
            pb[(size_t)(rbase + i) * 128 + col] = acc[nf][i];
    }
}

// ------- reduce split-K partials + optional bias + optional relu -------
__global__ void reduce_kernel(const float* __restrict__ pbuf, int S, size_t MC,
                              const float* __restrict__ bias, int relu,
                              float* __restrict__ dst) {
    size_t idx = ((size_t)blockIdx.x * 256 + threadIdx.x) * 4;
    if (idx >= MC) return;
    float4 v = *(const float4*)(pbuf + idx);
    for (int s = 1; s < S; s++) {
        float4 t = *(const float4*)(pbuf + (size_t)s * MC + idx);
        v.x += t.x; v.y += t.y; v.z += t.z; v.w += t.w;
    }
    if (bias) {
        int c = (int)(idx & 127);
        v.x += bias[c]; v.y += bias[c + 1]; v.z += bias[c + 2]; v.w += bias[c + 3];
    }
    if (relu) {
        v.x = v.x > 0.f ? v.x : 0.f; v.y = v.y > 0.f ? v.y : 0.f;
        v.z = v.z > 0.f ? v.z : 0.f; v.w = v.w > 0.f ? v.w : 0.f;
    }
    *(float4*)(dst + idx) = v;
}

// ------- FUSED: split-K reduce + relu + next-level score/key/rank (2 rows/block) -------
__global__ void reduce_score_kernel(const float* __restrict__ pbuf, int S, int Mrows,
                                    const float* __restrict__ w, float* __restrict__ xout,
                                    float* __restrict__ score,
                                    unsigned long long* __restrict__ keys,
                                    int* __restrict__ rank) {
    __shared__ float pd[4], pw[4];
    int t = threadIdx.x;
    int row = blockIdx.x * 2 + (t >> 7);
    int col = t & 127;
    size_t o = (size_t)row * 128 + col;
    float v = pbuf[o];
    for (int s = 1; s < S; s++) v += pbuf[(size_t)s * Mrows * 128 + o];
    v = v > 0.f ? v : 0.f;
    xout[o] = v;
    float wv = w[col];
    float dp = v * wv, w2 = wv * wv;
#pragma unroll
    for (int d2 = 1; d2 < 64; d2 <<= 1) {
        dp += __shfl_xor(dp, d2, 64);
        w2 += __shfl_xor(w2, d2, 64);
    }
    int wid = t >> 6;
    if ((t & 63) == 0) { pd[wid] = dp; pw[wid] = w2; }
    __syncthreads();
    if ((t & 127) == 0) {
        int b = wid;  // 0 or 2
        double dot = (double)pd[b] + (double)pd[b + 1];
        double nw = sqrt((double)pw[b] + (double)pw[b + 1]);
        float sc = (float)tanh(dot / nw);
        score[row] = sc;
        unsigned bu = __float_as_uint(sc);
        unsigned ord = (bu & 0x80000000u) ? ~bu : (bu | 0x80000000u);
        keys[row] = ((unsigned long long)(~ord) << 32) | (unsigned)row;
        rank[row] = 0;
    }
}

extern "C" void kernel_launch(void* const* d_in, const int* in_sizes, int n_in,
                              void* d_out, int out_size, void* d_ws, size_t ws_size,
                              hipStream_t stream) {
    const float* feat = (const float*)d_in[0];
    const float* H    = (const float*)d_in[1];
    const float* p_w[3]  = {(const float*)d_in[2], (const float*)d_in[3], (const float*)d_in[4]};
    const float* Wd[3]   = {(const float*)d_in[5], (const float*)d_in[7], (const float*)d_in[9]};
    const float* bd[3]   = {(const float*)d_in[6], (const float*)d_in[8], (const float*)d_in[10]};
    const float* Wu[3]   = {(const float*)d_in[11], (const float*)d_in[13], (const float*)d_in[15]};
    const float* bu[3]   = {(const float*)d_in[12], (const float*)d_in[14], (const float*)d_in[16]};
    float* out = (float*)d_out;

    // ---- workspace carving ----
    char* wsp = (char*)d_ws;
    size_t off = 0;
    auto alloc = [&](size_t nbytes) { void* p = wsp + off; off += (nbytes + 255) & ~255ull; return p; };
    float* Hg0 = (float*)alloc(4096ull * 4096 * 4);
    float* Hg1 = (float*)alloc(2048ull * 2048 * 4);
    float* Hg2 = (float*)alloc(1024ull * 1024 * 4);
    float* x1  = (float*)alloc(4096ull * D * 4);
    float* x2  = (float*)alloc(2048ull * D * 4);
    float* xc  = (float*)alloc(4096ull * D * 4);
    short* ttb = (short*)alloc(128ull * 8192 * 2);
    float* pbuf = (float*)alloc(8ull * 4096 * 128 * 4);   // split-K partial slices (16.8 MB)
    short* Bth = (short*)alloc(128ull * 4096 * 2);
    short* Btm = (short*)alloc(128ull * 4096 * 2);
    short* Btl = (short*)alloc(128ull * 4096 * 2);
    short* Wth = (short*)alloc(3ull * 128 * 128 * 2);
    short* Wtm = (short*)alloc(3ull * 128 * 128 * 2);
    short* Wtl = (short*)alloc(3ull * 128 * 128 * 2);
    short* Wut = (short*)alloc(3ull * 128 * 128 * 2);
    float* score = (float*)alloc(8192 * 4);
    float* gate  = (float*)alloc(4096 * 4);
    unsigned long long* keys = (unsigned long long*)alloc(8192 * 8);
    int* rank = (int*)alloc(8192 * 4);
    int* perm0 = (int*)alloc(4096 * 4);
    int* perm1 = (int*)alloc(2048 * 4);
    int* perm2 = (int*)alloc(1024 * 4);
    int* sperm0 = (int*)alloc(4096 * 4);
    int* sperm1 = (int*)alloc(2048 * 4);
    int* sperm2 = (int*)alloc(1024 * 4);
    int* pos0 = (int*)alloc(4096 * 4);
    int* pos1 = (int*)alloc(2048 * 4);
    int* pos2 = (int*)alloc(1024 * 4);
    int* sel0 = (int*)alloc(8192 * 4);
    int* sel1 = (int*)alloc(4096 * 4);
    int* sel2 = (int*)alloc(2048 * 4);

    const int ks[3] = {4096, 2048, 1024};
    const int ns[3] = {8192, 4096, 2048};
    int* perms[3] = {perm0, perm1, perm2};
    int* sperms[3] = {sperm0, sperm1, sperm2};
    int* poss[3] = {pos0, pos1, pos2};
    int* sels[3] = {sel0, sel1, sel2};
    float* Hgs[3] = {Hg0, Hg1, Hg2};
    const float* xin[3] = {feat, x1, x2};
    float* xout[3] = {x1, x2, xc};
    const int dS[3] = {8, 8, 16};

    // ---- one-shot weight prep (all 6 transposes in one launch) ----
    dim3 pg(4, 4, 6);
    weight_prep_kernel<<<pg, 256, 0, stream>>>(Wd[0], Wd[1], Wd[2], Wu[0], Wu[1], Wu[2],
                                               Wth, Wtm, Wtl, Wut);
    // ---- level-0 score ----
    score_kernel<<<8192, 128, 0, stream>>>(feat, p_w[0], score, keys, rank, 8192);

    // ---------------- down path (fp32-accurate split6 MFMA) ----------------
    for (int i = 0; i < 3; i++) {
        int n = ns[i], k = ks[i];
        int lg = (k == 4096) ? 12 : (k == 2048 ? 11 : 10);
        dim3 rg(n / 1024, n / 512);
        rank_count_kernel<<<rg, 256, 0, stream>>>(keys, rank, n);
        topk_finalize_kernel<<<1, 1024, 0, stream>>>(score, rank, n, k, perms[i], gate,
                                                     sperms[i], poss[i], sels[i]);
        h_gather_kernel<<<(k * k) / 256, 256, 0, stream>>>(H, perms[i], sperms[i], Hgs[i], k, lg);
        // T = (gate*x[perm]) @ Wd + bd   (split6, K=128, S=2; pool fused into A-stage)
        dim3 g1(k / 64, 2);
        mfma_split6_pool_kernel<<<g1, 256, 0, stream>>>(xin[i], perms[i], gate,
                                                        Wth + i * 16384, Wtm + i * 16384,
                                                        Wtl + i * 16384, pbuf, k, 128, 64);
        // fused: reduce(S=2)+bias+pos-permute+transpose+split3 -> B planes
        dim3 tg(k / 32, 4);
        reduce_split_transpose_kernel<<<tg, 256, 0, stream>>>(pbuf, 2, k, bd[i], poss[i],
                                                              Bth, Btm, Btl, k);
        // xout = relu(Hg' @ T')  (split6, K=k, S=dS[i])
        dim3 g2(k / 64, dS[i]);
        mfma_split6_kernel<<<g2, 256, 0, stream>>>(Hgs[i], Bth, Btm, Btl, pbuf, k, k, k / dS[i]);
        if (i < 2)
            reduce_score_kernel<<<k / 2, 256, 0, stream>>>(pbuf, dS[i], k, p_w[i + 1],
                                                           xout[i], score, keys, rank);
        else
            reduce_kernel<<<(k * 128 / 4 + 255) / 256, 256, 0, stream>>>(pbuf, dS[i],
                                                                         (size_t)k * 128,
                                                                         nullptr, 1, xout[i]);
    }

    // ---------------- up path (bf16 MFMA) ----------------
    const float* res[3] = {x2, x1, feat};
    const float* graphs[3] = {Hg1, Hg0, H};
    const int* upos[3] = {pos1, pos0, nullptr};   // T-row permute matching graph's column order
    const int* usel[3] = {sel2, sel1, sel0};      // rank array for fused residual+scatter
    const int un[3] = {2048, 4096, 8192};
    const int uS[3] = {8, 8, 4};
    for (int i = 0; i < 3; i++) {
        int n = un[i];
        // T = (res + scatter(xc)) @ Wu + bu  (bf16, K=128, S=2; add+scatter fused in A-stage)
        dim3 g1(n / 64, 2);
        mfma_gemm1_add_kernel<<<g1, 256, 0, stream>>>(res[i], xc, usel[i],
                                                      Wut + i * 16384, pbuf, n, 128, 64);
        // fused: reduce(S=2)+bias+pos-permute+transpose+cvt -> ttb
        dim3 tg(n / 32, 4);
        reduce_transpose_cvt_kernel<<<tg, 256, 0, stream>>>(pbuf, 2, n, bu[i], upos[i], ttb, n);
        // dst = relu(graph' @ T')  (bf16, K=n)
        dim3 g2(n / 64, uS[i]);
        mfma_gemm1_kernel<<<g2, 256, 0, stream>>>(graphs[i], ttb, pbuf, n, n, n / uS[i]);
        float* dst = (i == 2) ? out : xc;
        reduce_kernel<<<(n * 128 / 4 + 255) / 256, 256, 0, stream>>>(pbuf, uS[i],
                                                                     (size_t)n * 128,
                                                                     nullptr, 1, dst);
    }
    (void)in_sizes; (void)n_in; (void)out_size; (void)ws_size;
}

// Round 4
// 723.721 us; speedup vs baseline: 1.3863x; 1.0714x over previous
//
#include <hip/hip_runtime.h>
#include <math.h>

#define N0 8192
#define D 128

typedef __attribute__((ext_vector_type(8))) short short8;
typedef __attribute__((ext_vector_type(4))) float f32x4;

__device__ inline short f2bf(float f) {
    unsigned u = __float_as_uint(f);
    u = u + 0x7fffu + ((u >> 16) & 1u);
    return (short)(u >> 16);
}

// RNE 3-way bf16 split: v ~= h + m + l, residual ~2^-24 relative
__device__ inline void split3(float v, short& h, short& m, short& l) {
    unsigned u = __float_as_uint(v);
    unsigned hs = (u + 0x7fffu + ((u >> 16) & 1u)) >> 16;
    h = (short)hs;
    float rem = v - __uint_as_float(hs << 16);     // exact
    unsigned ur = __float_as_uint(rem);
    unsigned ms = (ur + 0x7fffu + ((ur >> 16) & 1u)) >> 16;
    m = (short)ms;
    float rem2 = rem - __uint_as_float(ms << 16);  // exact
    unsigned u2 = __float_as_uint(rem2);
    l = (short)((u2 + 0x7fffu + ((u2 >> 16) & 1u)) >> 16);
}

// ------- score (level 0 only): s[i] = tanh((x[i]·w)/||w||); emits key + rank=0 -------
__global__ void score_kernel(const float* __restrict__ x, const float* __restrict__ w,
                             float* __restrict__ score, unsigned long long* __restrict__ keys,
                             int* __restrict__ rank, int n) {
    __shared__ float red[128];
    __shared__ float red2[128];
    int row = blockIdx.x;
    int t = threadIdx.x;
    float wv = w[t];
    float xv = x[row * D + t];
    red[t] = xv * wv;
    red2[t] = wv * wv;
    __syncthreads();
    for (int s = 64; s > 0; s >>= 1) {
        if (t < s) { red[t] += red[t + s]; red2[t] += red2[t + s]; }
        __syncthreads();
    }
    if (t == 0) {
        double a = (double)red[0] / sqrt((double)red2[0]);
        float sc = (float)tanh(a);
        score[row] = sc;
        unsigned b = __float_as_uint(sc);
        unsigned ord = (b & 0x80000000u) ? ~b : (b | 0x80000000u);
        keys[row] = ((unsigned long long)(~ord) << 32) | (unsigned)row;
        rank[row] = 0;
    }
}

// ------- parallel exact rank: rank[i] = #{j : key[j] < key[i]} (keys unique) -------
__global__ __launch_bounds__(256) void rank_count_kernel(
        const unsigned long long* __restrict__ keys, int* __restrict__ rank, int n) {
    __shared__ __align__(16) unsigned long long kt[512];
    int tid = threadIdx.x;
    int i0 = blockIdx.x * 1024;
    int j0 = blockIdx.y * 512;
    unsigned long long myk0 = keys[i0 + tid];
    unsigned long long myk1 = keys[i0 + 256 + tid];
    unsigned long long myk2 = keys[i0 + 512 + tid];
    unsigned long long myk3 = keys[i0 + 768 + tid];
    *(ulonglong2*)&kt[2 * tid] = *(const ulonglong2*)&keys[j0 + 2 * tid];
    __syncthreads();
    int c0 = 0, c1 = 0, c2 = 0, c3 = 0;
#pragma unroll 4
    for (int j = 0; j < 256; j++) {
        unsigned long long a = kt[2 * j], b = kt[2 * j + 1];
        c0 += (a < myk0) + (b < myk0);
        c1 += (a < myk1) + (b < myk1);
        c2 += (a < myk2) + (b < myk2);
        c3 += (a < myk3) + (b < myk3);
    }
    atomicAdd(&rank[i0 + tid], c0);
    atomicAdd(&rank[i0 + 256 + tid], c1);
    atomicAdd(&rank[i0 + 512 + tid], c2);
    atomicAdd(&rank[i0 + 768 + tid], c3);
}

// ------- finalize top-k from ranks: perm/gate/selg + compacted sperm/pos -------
__global__ void topk_finalize_kernel(const float* __restrict__ score, const int* __restrict__ rank,
                                     int n, int k, int* __restrict__ perm, float* __restrict__ gate,
                                     int* __restrict__ sperm, int* __restrict__ pos,
                                     int* __restrict__ selg) {
    __shared__ int scanb[1024];
    int t = threadIdx.x;
    int per = n >> 10;
    int base = t * per;
    int cnt = 0;
#pragma unroll 8
    for (int j = 0; j < 8; j++) {
        if (j < per) {
            int i = base + j;
            int r = rank[i];
            if (r < k) { cnt++; perm[r] = i; gate[r] = score[i]; selg[i] = r; }
            else selg[i] = -1;
        }
    }
    scanb[t] = cnt;
    __syncthreads();
    for (int s = 1; s < 1024; s <<= 1) {
        int v = (t >= s) ? scanb[t - s] : 0;
        __syncthreads();
        scanb[t] += v;
        __syncthreads();
    }
    int c = scanb[t] - cnt;  // exclusive prefix of selected-count
#pragma unroll 8
    for (int j = 0; j < 8; j++) {
        if (j < per) {
            int i = base + j;
            int r = rank[i];
            if (r < k) { sperm[c] = i; pos[c] = r; c++; }
        }
    }
}

// ---------------- Hg[r][c] = H[perm[r]][sperm[c]]  (ascending cols -> coalesced) ----
__global__ void h_gather_kernel(const float* __restrict__ H, const int* __restrict__ perm,
                                const int* __restrict__ sperm, float* __restrict__ Hg,
                                int k, int lg) {
    int idx = blockIdx.x * blockDim.x + threadIdx.x;
    int r = idx >> lg;
    int c = idx & (k - 1);
    if (r >= k) return;
    Hg[idx] = H[(size_t)perm[r] * N0 + sperm[c]];
}

// ------- one-shot weight prep: z<3 split-transpose Wd[z]; z>=3 cvt-transpose Wu[z-3] -----
__global__ void weight_prep_kernel(const float* __restrict__ W0, const float* __restrict__ W1,
                                   const float* __restrict__ W2, const float* __restrict__ W3,
                                   const float* __restrict__ W4, const float* __restrict__ W5,
                                   short* __restrict__ Wth, short* __restrict__ Wtm,
                                   short* __restrict__ Wtl, short* __restrict__ Wut) {
    __shared__ float tile[32][33];
    const float* srcs[6] = {W0, W1, W2, W3, W4, W5};
    int z = blockIdx.z;
    const float* T = srcs[z];
    int tx = threadIdx.x & 31, ty = threadIdx.x >> 5;
    int r0 = blockIdx.x * 32, c0 = blockIdx.y * 32;
#pragma unroll
    for (int kk = 0; kk < 4; kk++)
        tile[ty + kk * 8][tx] = T[(r0 + ty + kk * 8) * 128 + c0 + tx];
    __syncthreads();
    if (z < 3) {
        short* th = Wth + z * 16384; short* tm = Wtm + z * 16384; short* tl = Wtl + z * 16384;
#pragma unroll
        for (int kk = 0; kk < 4; kk++) {
            float v = tile[tx][ty + kk * 8];
            short h, m, l;
            split3(v, h, m, l);
            int o = (c0 + ty + kk * 8) * 128 + r0 + tx;
            th[o] = h; tm[o] = m; tl[o] = l;
        }
    } else {
        short* tt = Wut + (z - 3) * 16384;
#pragma unroll
        for (int kk = 0; kk < 4; kk++)
            tt[(c0 + ty + kk * 8) * 128 + r0 + tx] = f2bf(tile[tx][ty + kk * 8]);
    }
}

// ------- FUSED: split-K reduce + bias + (pos row-permute) + transpose + split3 -------
__global__ void reduce_split_transpose_kernel(const float* __restrict__ pbuf, int S, int M,
        const float* __restrict__ bias, const int* __restrict__ pos,
        short* __restrict__ Th, short* __restrict__ Tm, short* __restrict__ Tl, int n) {
    __shared__ float tile[32][33];
    int tx = threadIdx.x & 31, ty = threadIdx.x >> 5;
    int r0 = blockIdx.x * 32, c0 = blockIdx.y * 32;
#pragma unroll
    for (int kk = 0; kk < 4; kk++) {
        int rr = r0 + ty + kk * 8;
        int sr = pos ? pos[rr] : rr;
        size_t o = (size_t)sr * 128 + c0 + tx;
        float v = pbuf[o];
        for (int s = 1; s < S; s++) v += pbuf[(size_t)s * M * 128 + o];
        tile[ty + kk * 8][tx] = v + bias[c0 + tx];
    }
    __syncthreads();
#pragma unroll
    for (int kk = 0; kk < 4; kk++) {
        float v = tile[tx][ty + kk * 8];
        short h, m, l;
        split3(v, h, m, l);
        size_t o = (size_t)(c0 + ty + kk * 8) * n + r0 + tx;
        Th[o] = h; Tm[o] = m; Tl[o] = l;
    }
}

// ------- FUSED: split-K reduce + bias + (pos row-permute) + transpose + bf16 cvt -------
__global__ void reduce_transpose_cvt_kernel(const float* __restrict__ pbuf, int S, int M,
        const float* __restrict__ bias, const int* __restrict__ pos,
        short* __restrict__ Tt, int n) {
    __shared__ float tile[32][33];
    int tx = threadIdx.x & 31, ty = threadIdx.x >> 5;
    int r0 = blockIdx.x * 32, c0 = blockIdx.y * 32;
#pragma unroll
    for (int kk = 0; kk < 4; kk++) {
        int rr = r0 + ty + kk * 8;
        int sr = pos ? pos[rr] : rr;
        size_t o = (size_t)sr * 128 + c0 + tx;
        float v = pbuf[o];
        for (int s = 1; s < S; s++) v += pbuf[(size_t)s * M * 128 + o];
        tile[ty + kk * 8][tx] = v + bias[c0 + tx];
    }
    __syncthreads();
#pragma unroll
    for (int kk = 0; kk < 4; kk++)
        Tt[(size_t)(c0 + ty + kk * 8) * n + r0 + tx] = f2bf(tile[tx][ty + kk * 8]);
}

// ------- fp32-accurate MFMA gemm via 3-way bf16 split, 6 products (generic A) -------
// Software-pipelined: register-prefetch of next k-tile overlaps global latency with MFMA.
__global__ __launch_bounds__(256) void mfma_split6_kernel(
        const float* __restrict__ A, const short* __restrict__ Bh,
        const short* __restrict__ Bm, const short* __restrict__ Bl,
        float* __restrict__ pbuf, int M, int K, int chunk) {
    __shared__ __align__(16) short Ah[64 * 40], Am[64 * 40], Al[64 * 40];
    __shared__ __align__(16) short Bhs[128 * 40], Bms[128 * 40], Bls[128 * 40];
    int tid = threadIdx.x;
    int w = tid >> 6, lane = tid & 63;
    int m16 = lane & 15, kq = lane >> 4;
    int bm = blockIdx.x;
    int kbeg = blockIdx.y * chunk;

    f32x4 acc[8];
#pragma unroll
    for (int i = 0; i < 8; i++) acc[i] = (f32x4){0.f, 0.f, 0.f, 0.f};

    const float* Ab = A + (size_t)bm * 64 * K;
    int arow = tid >> 2, acg = (tid & 3) * 8;

    float4 pa0, pa1; short8 ph0, ph1, pm0, pm1, pl0, pl1;
    float4 qa0, qa1; short8 qh0, qh1, qm0, qm1, ql0, ql1;

    auto LOAD = [&](int k0, float4& a0, float4& a1, short8& h0, short8& h1,
                    short8& m0, short8& m1, short8& l0, short8& l1) {
        const float* src = Ab + (size_t)arow * K + k0 + acg;
        a0 = *(const float4*)src;
        a1 = *(const float4*)(src + 4);
        size_t go = (size_t)arow * K + k0 + acg;
        size_t go2 = go + (size_t)64 * K;
        h0 = *(const short8*)&Bh[go]; h1 = *(const short8*)&Bh[go2];
        m0 = *(const short8*)&Bm[go]; m1 = *(const short8*)&Bm[go2];
        l0 = *(const short8*)&Bl[go]; l1 = *(const short8*)&Bl[go2];
    };
    auto STORE = [&](float4& a0, float4& a1, short8& h0, short8& h1,
                     short8& m0, short8& m1, short8& l0, short8& l1) {
        float vv[8] = {a0.x, a0.y, a0.z, a0.w, a1.x, a1.y, a1.z, a1.w};
        short8 th, tm, tl;
#pragma unroll
        for (int j = 0; j < 8; j++) { short h, m, l; split3(vv[j], h, m, l); th[j] = h; tm[j] = m; tl[j] = l; }
        *(short8*)&Ah[arow * 40 + acg] = th;
        *(short8*)&Am[arow * 40 + acg] = tm;
        *(short8*)&Al[arow * 40 + acg] = tl;
        int lo = arow * 40 + acg, lo2 = lo + 64 * 40;
        *(short8*)&Bhs[lo] = h0; *(short8*)&Bhs[lo2] = h1;
        *(short8*)&Bms[lo] = m0; *(short8*)&Bms[lo2] = m1;
        *(short8*)&Bls[lo] = l0; *(short8*)&Bls[lo2] = l1;
    };
    auto COMPUTE = [&]() {
        int ao = (w * 16 + m16) * 40 + kq * 8;
        short8 a_h = *(short8*)&Ah[ao];
        short8 a_m = *(short8*)&Am[ao];
        short8 a_l = *(short8*)&Al[ao];
#pragma unroll
        for (int nf = 0; nf < 8; nf++) {
            int bo = (nf * 16 + m16) * 40 + kq * 8;
            short8 b_h = *(short8*)&Bhs[bo];
            short8 b_m = *(short8*)&Bms[bo];
            short8 b_l = *(short8*)&Bls[bo];
            acc[nf] = __builtin_amdgcn_mfma_f32_16x16x32_bf16(a_h, b_h, acc[nf], 0, 0, 0);
            acc[nf] = __builtin_amdgcn_mfma_f32_16x16x32_bf16(a_h, b_m, acc[nf], 0, 0, 0);
            acc[nf] = __builtin_amdgcn_mfma_f32_16x16x32_bf16(a_m, b_h, acc[nf], 0, 0, 0);
            acc[nf] = __builtin_amdgcn_mfma_f32_16x16x32_bf16(a_h, b_l, acc[nf], 0, 0, 0);
            acc[nf] = __builtin_amdgcn_mfma_f32_16x16x32_bf16(a_l, b_h, acc[nf], 0, 0, 0);
            acc[nf] = __builtin_amdgcn_mfma_f32_16x16x32_bf16(a_m, b_m, acc[nf], 0, 0, 0);
        }
    };

    int nt = chunk >> 5;  // even (chunk is a multiple of 64)
    LOAD(kbeg, pa0, pa1, ph0, ph1, pm0, pm1, pl0, pl1);
    for (int t = 0; t < nt; t += 2) {
        int k0 = kbeg + (t << 5);
        STORE(pa0, pa1, ph0, ph1, pm0, pm1, pl0, pl1);
        LOAD(k0 + 32, qa0, qa1, qh0, qh1, qm0, qm1, ql0, ql1);
        __syncthreads();
        COMPUTE();
        __syncthreads();
        STORE(qa0, qa1, qh0, qh1, qm0, qm1, ql0, ql1);
        if (t + 2 < nt) LOAD(k0 + 64, pa0, pa1, ph0, ph1, pm0, pm1, pl0, pl1);
        __syncthreads();
        COMPUTE();
        __syncthreads();
    }
    float* pb = pbuf + (size_t)blockIdx.y * M * 128;
    int rbase = bm * 64 + w * 16 + kq * 4;
#pragma unroll
    for (int nf = 0; nf < 8; nf++) {
        int col = nf * 16 + m16;
#pragma unroll
        for (int i = 0; i < 4; i++)
            pb[(size_t)(rbase + i) * 128 + col] = acc[nf][i];
    }
}

// ------- split6 GEMM with FUSED pool-gather A: A[j] = x[perm[j]] * gate[j], K=128 -------
__global__ __launch_bounds__(256) void mfma_split6_pool_kernel(
        const float* __restrict__ x, const int* __restrict__ perm, const float* __restrict__ gate,
        const short* __restrict__ Bh, const short* __restrict__ Bm, const short* __restrict__ Bl,
        float* __restrict__ pbuf, int M, int K, int chunk) {
    __shared__ __align__(16) short Ah[64 * 40], Am[64 * 40], Al[64 * 40];
    __shared__ __align__(16) short Bhs[128 * 40], Bms[128 * 40], Bls[128 * 40];
    int tid = threadIdx.x;
    int w = tid >> 6, lane = tid & 63;
    int m16 = lane & 15, kq = lane >> 4;
    int bm = blockIdx.x;
    int kbeg = blockIdx.y * chunk;

    f32x4 acc[8];
#pragma unroll
    for (int i = 0; i < 8; i++) acc[i] = (f32x4){0.f, 0.f, 0.f, 0.f};

    int arow = tid >> 2, acg = (tid & 3) * 8;
    int grow = bm * 64 + arow;
    int prow = perm[grow];
    float g = gate[grow];

    float4 pa0, pa1; short8 ph0, ph1, pm0, pm1, pl0, pl1;
    float4 qa0, qa1; short8 qh0, qh1, qm0, qm1, ql0, ql1;

    auto LOAD = [&](int k0, float4& a0, float4& a1, short8& h0, short8& h1,
                    short8& m0, short8& m1, short8& l0, short8& l1) {
        const float* src = x + (size_t)prow * K + k0 + acg;
        a0 = *(const float4*)src;
        a1 = *(const float4*)(src + 4);
        size_t go = (size_t)arow * K + k0 + acg;
        size_t go2 = go + (size_t)64 * K;
        h0 = *(const short8*)&Bh[go]; h1 = *(const short8*)&Bh[go2];
        m0 = *(const short8*)&Bm[go]; m1 = *(const short8*)&Bm[go2];
        l0 = *(const short8*)&Bl[go]; l1 = *(const short8*)&Bl[go2];
    };
    auto STORE = [&](float4& a0, float4& a1, short8& h0, short8& h1,
                     short8& m0, short8& m1, short8& l0, short8& l1) {
        float vv[8] = {a0.x * g, a0.y * g, a0.z * g, a0.w * g,
                       a1.x * g, a1.y * g, a1.z * g, a1.w * g};
        short8 th, tm, tl;
#pragma unroll
        for (int j = 0; j < 8; j++) { short h, m, l; split3(vv[j], h, m, l); th[j] = h; tm[j] = m; tl[j] = l; }
        *(short8*)&Ah[arow * 40 + acg] = th;
        *(short8*)&Am[arow * 40 + acg] = tm;
        *(short8*)&Al[arow * 40 + acg] = tl;
        int lo = arow * 40 + acg, lo2 = lo + 64 * 40;
        *(short8*)&Bhs[lo] = h0; *(short8*)&Bhs[lo2] = h1;
        *(short8*)&Bms[lo] = m0; *(short8*)&Bms[lo2] = m1;
        *(short8*)&Bls[lo] = l0; *(short8*)&Bls[lo2] = l1;
    };
    auto COMPUTE = [&]() {
        int ao = (w * 16 + m16) * 40 + kq * 8;
        short8 a_h = *(short8*)&Ah[ao];
        short8 a_m = *(short8*)&Am[ao];
        short8 a_l = *(short8*)&Al[ao];
#pragma unroll
        for (int nf = 0; nf < 8; nf++) {
            int bo = (nf * 16 + m16) * 40 + kq * 8;
            short8 b_h = *(short8*)&Bhs[bo];
            short8 b_m = *(short8*)&Bms[bo];
            short8 b_l = *(short8*)&Bls[bo];
            acc[nf] = __builtin_amdgcn_mfma_f32_16x16x32_bf16(a_h, b_h, acc[nf], 0, 0, 0);
            acc[nf] = __builtin_amdgcn_mfma_f32_16x16x32_bf16(a_h, b_m, acc[nf], 0, 0, 0);
            acc[nf] = __builtin_amdgcn_mfma_f32_16x16x32_bf16(a_m, b_h, acc[nf], 0, 0, 0);
            acc[nf] = __builtin_amdgcn_mfma_f32_16x16x32_bf16(a_h, b_l, acc[nf], 0, 0, 0);
            acc[nf] = __builtin_amdgcn_mfma_f32_16x16x32_bf16(a_l, b_h, acc[nf], 0, 0, 0);
            acc[nf] = __builtin_amdgcn_mfma_f32_16x16x32_bf16(a_m, b_m, acc[nf], 0, 0, 0);
        }
    };

    int nt = chunk >> 5;
    LOAD(kbeg, pa0, pa1, ph0, ph1, pm0, pm1, pl0, pl1);
    for (int t = 0; t < nt; t += 2) {
        int k0 = kbeg + (t << 5);
        STORE(pa0, pa1, ph0, ph1, pm0, pm1, pl0, pl1);
        LOAD(k0 + 32, qa0, qa1, qh0, qh1, qm0, qm1, ql0, ql1);
        __syncthreads();
        COMPUTE();
        __syncthreads();
        STORE(qa0, qa1, qh0, qh1, qm0, qm1, ql0, ql1);
        if (t + 2 < nt) LOAD(k0 + 64, pa0, pa1, ph0, ph1, pm0, pm1, pl0, pl1);
        __syncthreads();
        COMPUTE();
        __syncthreads();
    }
    float* pb = pbuf + (size_t)blockIdx.y * M * 128;
    int rbase = bm * 64 + w * 16 + kq * 4;
#pragma unroll
    for (int nf = 0; nf < 8; nf++) {
        int col = nf * 16 + m16;
#pragma unroll
        for (int i = 0; i < 4; i++)
            pb[(size_t)(rbase + i) * 128 + col] = acc[nf][i];
    }
}

// ------- bf16 MFMA gemm (1 product, generic A), register-prefetch pipelined -------
__global__ __launch_bounds__(256) void mfma_gemm1_kernel(
        const float* __restrict__ A, const short* __restrict__ Bt,
        float* __restrict__ pbuf, int M, int K, int chunk) {
    __shared__ __align__(16) short As[64 * 40];
    __shared__ __align__(16) short Bs[128 * 40];
    int tid = threadIdx.x;
    int w = tid >> 6, lane = tid & 63;
    int m16 = lane & 15, kq = lane >> 4;
    int bm = blockIdx.x;
    int kbeg = blockIdx.y * chunk;

    f32x4 acc[8];
#pragma unroll
    for (int i = 0; i < 8; i++) acc[i] = (f32x4){0.f, 0.f, 0.f, 0.f};

    const float* Ab = A + (size_t)bm * 64 * K;
    int arow = tid >> 2, acg = (tid & 3) * 8;

    float4 pa0, pa1; short8 pb0, pb1;
    float4 qa0, qa1; short8 qb0, qb1;

    auto LOAD = [&](int k0, float4& a0, float4& a1, short8& b0, short8& b1) {
        const float* src = Ab + (size_t)arow * K + k0 + acg;
        a0 = *(const float4*)src;
        a1 = *(const float4*)(src + 4);
        size_t go = (size_t)arow * K + k0 + acg;
        b0 = *(const short8*)&Bt[go];
        b1 = *(const short8*)&Bt[go + (size_t)64 * K];
    };
    auto STORE = [&](float4& a0, float4& a1, short8& b0, short8& b1) {
        short8 t;
        t[0] = f2bf(a0.x); t[1] = f2bf(a0.y); t[2] = f2bf(a0.z); t[3] = f2bf(a0.w);
        t[4] = f2bf(a1.x); t[5] = f2bf(a1.y); t[6] = f2bf(a1.z); t[7] = f2bf(a1.w);
        *(short8*)&As[arow * 40 + acg] = t;
        int lo = arow * 40 + acg;
        *(short8*)&Bs[lo] = b0;
        *(short8*)&Bs[lo + 64 * 40] = b1;
    };
    auto COMPUTE = [&]() {
        short8 a = *(short8*)&As[(w * 16 + m16) * 40 + kq * 8];
#pragma unroll
        for (int nf = 0; nf < 8; nf++) {
            short8 b = *(short8*)&Bs[(nf * 16 + m16) * 40 + kq * 8];
            acc[nf] = __builtin_amdgcn_mfma_f32_16x16x32_bf16(a, b, acc[nf], 0, 0, 0);
        }
    };

    int nt = chunk >> 5;
    LOAD(kbeg, pa0, pa1, pb0, pb1);
    for (int t = 0; t < nt; t += 2) {
        int k0 = kbeg + (t << 5);
        STORE(pa0, pa1, pb0, pb1);
        LOAD(k0 + 32, qa0, qa1, qb0, qb1);
        __syncthreads();
        COMPUTE();
        __syncthreads();
        STORE(qa0, qa1, qb0, qb1);
        if (t + 2 < nt) LOAD(k0 + 64, pa0, pa1, pb0, pb1);
        __syncthreads();
        COMPUTE();
        __syncthreads();
    }
    float* pb = pbuf + (size_t)blockIdx.y * M * 128;
    int rbase = bm * 64 + w * 16 + kq * 4;
#pragma unroll
    for (int nf = 0; nf < 8; nf++) {
        int col = nf * 16 + m16;
#pragma unroll
        for (int i = 0; i < 4; i++)
            pb[(size_t)(rbase + i) * 128 + col] = acc[nf][i];
    }
}

// ------- bf16 gemm, FUSED residual+scatter A, register-prefetch pipelined -------
__global__ __launch_bounds__(256) void mfma_gemm1_add_kernel(
        const float* __restrict__ res, const float* __restrict__ xc, const int* __restrict__ selg,
        const short* __restrict__ Bt, float* __restrict__ pbuf, int M, int K, int chunk) {
    __shared__ __align__(16) short As[64 * 40];
    __shared__ __align__(16) short Bs[128 * 40];
    int tid = threadIdx.x;
    int w = tid >> 6, lane = tid & 63;
    int m16 = lane & 15, kq = lane >> 4;
    int bm = blockIdx.x;
    int kbeg = blockIdx.y * chunk;

    f32x4 acc[8];
#pragma unroll
    for (int i = 0; i < 8; i++) acc[i] = (f32x4){0.f, 0.f, 0.f, 0.f};

    int arow = tid >> 2, acg = (tid & 3) * 8;
    int grow = bm * 64 + arow;
    int r = selg[grow];

    float4 pa0, pa1, pu0, pu1; short8 pb0, pb1;
    float4 qa0, qa1, qu0, qu1; short8 qb0, qb1;

    auto LOAD = [&](int k0, float4& a0, float4& a1, float4& u0, float4& u1,
                    short8& b0, short8& b1) {
        const float* s1 = res + (size_t)grow * K + k0 + acg;
        a0 = *(const float4*)s1;
        a1 = *(const float4*)(s1 + 4);
        if (r >= 0) {
            const float* s2 = xc + (size_t)r * K + k0 + acg;
            u0 = *(const float4*)s2;
            u1 = *(const float4*)(s2 + 4);
        }
        size_t go = (size_t)arow * K + k0 + acg;
        b0 = *(const short8*)&Bt[go];
        b1 = *(const short8*)&Bt[go + (size_t)64 * K];
    };
    auto STORE = [&](float4& a0, float4& a1, float4& u0, float4& u1,
                     short8& b0, short8& b1) {
        float4 v0 = a0, v1 = a1;
        if (r >= 0) {
            v0.x += u0.x; v0.y += u0.y; v0.z += u0.z; v0.w += u0.w;
            v1.x += u1.x; v1.y += u1.y; v1.z += u1.z; v1.w += u1.w;
        }
        short8 t;
        t[0] = f2bf(v0.x); t[1] = f2bf(v0.y); t[2] = f2bf(v0.z); t[3] = f2bf(v0.w);
        t[4] = f2bf(v1.x); t[5] = f2bf(v1.y); t[6] = f2bf(v1.z); t[7] = f2bf(v1.w);
        *(short8*)&As[arow * 40 + acg] = t;
        int lo = arow * 40 + acg;
        *(short8*)&Bs[lo] = b0;
        *(short8*)&Bs[lo + 64 * 40] = b1;
    };
    auto COMPUTE = [&]() {
        short8 a = *(short8*)&As[(w * 16 + m16) * 40 + kq * 8];
#pragma unroll
        for (int nf = 0; nf < 8; nf++) {
            short8 b = *(short8*)&Bs[(nf * 16 + m16) * 40 + kq * 8];
            acc[nf] = __builtin_amdgcn_mfma_f32_16x16x32_bf16(a, b, acc[nf], 0, 0, 0);
        }
    };

    int nt = chunk >> 5;
    LOAD(kbeg, pa0, pa1, pu0, pu1, pb0, pb1);
    for (int t = 0; t < nt; t += 2) {
        int k0 = kbeg + (t << 5);
        STORE(pa0, pa1, pu0, pu1, pb0, pb1);
        LOAD(k0 + 32, qa0, qa1, qu0, qu1, qb0, qb1);
        __syncthreads();
        COMPUTE();
        __syncthreads();
        STORE(qa0, qa1, qu0, qu1, qb0, qb1);
        if (t + 2 < nt) LOAD(k0 + 64, pa0, pa1, pu0, pu1, pb0, pb1);
        __syncthreads();
        COMPUTE();
        __syncthreads();
    }
    float* pb = pbuf + (size_t)blockIdx.y * M * 128;
    int rbase = bm * 64 + w * 16 + kq * 4;
#pragma unroll
    for (int nf = 0; nf < 8; nf++) {
        int col = nf * 16 + m16;
#pragma unroll
        for (int i = 0; i < 4; i++)
            pb[(size_t)(rbase + i) * 128 + col] = acc[nf][i];
    }
}

// ------- reduce split-K partials + optional bias + optional relu -------
__global__ void reduce_kernel(const float* __restrict__ pbuf, int S, size_t MC,
                              const float* __restrict__ bias, int relu,
                              float* __restrict__ dst) {
    size_t idx = ((size_t)blockIdx.x * 256 + threadIdx.x) * 4;
    if (idx >= MC) return;
    float4 v = *(const float4*)(pbuf + idx);
    for (int s = 1; s < S; s++) {
        float4 t = *(const float4*)(pbuf + (size_t)s * MC + idx);
        v.x += t.x; v.y += t.y; v.z += t.z; v.w += t.w;
    }
    if (bias) {
        int c = (int)(idx & 127);
        v.x += bias[c]; v.y += bias[c + 1]; v.z += bias[c + 2]; v.w += bias[c + 3];
    }
    if (relu) {
        v.x = v.x > 0.f ? v.x : 0.f; v.y = v.y > 0.f ? v.y : 0.f;
        v.z = v.z > 0.f ? v.z : 0.f; v.w = v.w > 0.f ? v.w : 0.f;
    }
    *(float4*)(dst + idx) = v;
}

// ------- FUSED: split-K reduce + relu + next-level score/key/rank (2 rows/block) -------
__global__ void reduce_score_kernel(const float* __restrict__ pbuf, int S, int Mrows,
                                    const float* __restrict__ w, float* __restrict__ xout,
                                    float* __restrict__ score,
                                    unsigned long long* __restrict__ keys,
                                    int* __restrict__ rank) {
    __shared__ float pd[4], pw[4];
    int t = threadIdx.x;
    int row = blockIdx.x * 2 + (t >> 7);
    int col = t & 127;
    size_t o = (size_t)row * 128 + col;
    float v = pbuf[o];
    for (int s = 1; s < S; s++) v += pbuf[(size_t)s * Mrows * 128 + o];
    v = v > 0.f ? v : 0.f;
    xout[o] = v;
    float wv = w[col];
    float dp = v * wv, w2 = wv * wv;
#pragma unroll
    for (int d2 = 1; d2 < 64; d2 <<= 1) {
        dp += __shfl_xor(dp, d2, 64);
        w2 += __shfl_xor(w2, d2, 64);
    }
    int wid = t >> 6;
    if ((t & 63) == 0) { pd[wid] = dp; pw[wid] = w2; }
    __syncthreads();
    if ((t & 127) == 0) {
        int b = wid;  // 0 or 2
        double dot = (double)pd[b] + (double)pd[b + 1];
        double nw = sqrt((double)pw[b] + (double)pw[b + 1]);
        float sc = (float)tanh(dot / nw);
        score[row] = sc;
        unsigned bu = __float_as_uint(sc);
        unsigned ord = (bu & 0x80000000u) ? ~bu : (bu | 0x80000000u);
        keys[row] = ((unsigned long long)(~ord) << 32) | (unsigned)row;
        rank[row] = 0;
    }
}

extern "C" void kernel_launch(void* const* d_in, const int* in_sizes, int n_in,
                              void* d_out, int out_size, void* d_ws, size_t ws_size,
                              hipStream_t stream) {
    const float* feat = (const float*)d_in[0];
    const float* H    = (const float*)d_in[1];
    const float* p_w[3]  = {(const float*)d_in[2], (const float*)d_in[3], (const float*)d_in[4]};
    const float* Wd[3]   = {(const float*)d_in[5], (const float*)d_in[7], (const float*)d_in[9]};
    const float* bd[3]   = {(const float*)d_in[6], (const float*)d_in[8], (const float*)d_in[10]};
    const float* Wu[3]   = {(const float*)d_in[11], (const float*)d_in[13], (const float*)d_in[15]};
    const float* bu[3]   = {(const float*)d_in[12], (const float*)d_in[14], (const float*)d_in[16]};
    float* out = (float*)d_out;

    // ---- workspace carving ----
    char* wsp = (char*)d_ws;
    size_t off = 0;
    auto alloc = [&](size_t nbytes) { void* p = wsp + off; off += (nbytes + 255) & ~255ull; return p; };
    float* Hg0 = (float*)alloc(4096ull * 4096 * 4);
    float* Hg1 = (float*)alloc(2048ull * 2048 * 4);
    float* Hg2 = (float*)alloc(1024ull * 1024 * 4);
    float* x1  = (float*)alloc(4096ull * D * 4);
    float* x2  = (float*)alloc(2048ull * D * 4);
    float* xc  = (float*)alloc(4096ull * D * 4);
    short* ttb = (short*)alloc(128ull * 8192 * 2);
    float* pbuf = (float*)alloc(8ull * 4096 * 128 * 4);   // split-K partial slices (16.8 MB)
    short* Bth = (short*)alloc(128ull * 4096 * 2);
    short* Btm = (short*)alloc(128ull * 4096 * 2);
    short* Btl = (short*)alloc(128ull * 4096 * 2);
    short* Wth = (short*)alloc(3ull * 128 * 128 * 2);
    short* Wtm = (short*)alloc(3ull * 128 * 128 * 2);
    short* Wtl = (short*)alloc(3ull * 128 * 128 * 2);
    short* Wut = (short*)alloc(3ull * 128 * 128 * 2);
    float* score = (float*)alloc(8192 * 4);
    float* gate  = (float*)alloc(4096 * 4);
    unsigned long long* keys = (unsigned long long*)alloc(8192 * 8);
    int* rank = (int*)alloc(8192 * 4);
    int* perm0 = (int*)alloc(4096 * 4);
    int* perm1 = (int*)alloc(2048 * 4);
    int* perm2 = (int*)alloc(1024 * 4);
    int* sperm0 = (int*)alloc(4096 * 4);
    int* sperm1 = (int*)alloc(2048 * 4);
    int* sperm2 = (int*)alloc(1024 * 4);
    int* pos0 = (int*)alloc(4096 * 4);
    int* pos1 = (int*)alloc(2048 * 4);
    int* pos2 = (int*)alloc(1024 * 4);
    int* sel0 = (int*)alloc(8192 * 4);
    int* sel1 = (int*)alloc(4096 * 4);
    int* sel2 = (int*)alloc(2048 * 4);

    const int ks[3] = {4096, 2048, 1024};
    const int ns[3] = {8192, 4096, 2048};
    int* perms[3] = {perm0, perm1, perm2};
    int* sperms[3] = {sperm0, sperm1, sperm2};
    int* poss[3] = {pos0, pos1, pos2};
    int* sels[3] = {sel0, sel1, sel2};
    float* Hgs[3] = {Hg0, Hg1, Hg2};
    const float* xin[3] = {feat, x1, x2};
    float* xout[3] = {x1, x2, xc};
    const int dS[3] = {8, 8, 16};

    // ---- one-shot weight prep (all 6 transposes in one launch) ----
    dim3 pg(4, 4, 6);
    weight_prep_kernel<<<pg, 256, 0, stream>>>(Wd[0], Wd[1], Wd[2], Wu[0], Wu[1], Wu[2],
                                               Wth, Wtm, Wtl, Wut);
    // ---- level-0 score ----
    score_kernel<<<8192, 128, 0, stream>>>(feat, p_w[0], score, keys, rank, 8192);

    // ---------------- down path (fp32-accurate split6 MFMA) ----------------
    for (int i = 0; i < 3; i++) {
        int n = ns[i], k = ks[i];
        int lg = (k == 4096) ? 12 : (k == 2048 ? 11 : 10);
        dim3 rg(n / 1024, n / 512);
        rank_count_kernel<<<rg, 256, 0, stream>>>(keys, rank, n);
        topk_finalize_kernel<<<1, 1024, 0, stream>>>(score, rank, n, k, perms[i], gate,
                                                     sperms[i], poss[i], sels[i]);
        h_gather_kernel<<<(k * k) / 256, 256, 0, stream>>>(H, perms[i], sperms[i], Hgs[i], k, lg);
        // T = (gate*x[perm]) @ Wd + bd   (split6, K=128, S=2; pool fused into A-stage)
        dim3 g1(k / 64, 2);
        mfma_split6_pool_kernel<<<g1, 256, 0, stream>>>(xin[i], perms[i], gate,
                                                        Wth + i * 16384, Wtm + i * 16384,
                                                        Wtl + i * 16384, pbuf, k, 128, 64);
        // fused: reduce(S=2)+bias+pos-permute+transpose+split3 -> B planes
        dim3 tg(k / 32, 4);
        reduce_split_transpose_kernel<<<tg, 256, 0, stream>>>(pbuf, 2, k, bd[i], poss[i],
                                                              Bth, Btm, Btl, k);
        // xout = relu(Hg' @ T')  (split6, K=k, S=dS[i])
        dim3 g2(k / 64, dS[i]);
        mfma_split6_kernel<<<g2, 256, 0, stream>>>(Hgs[i], Bth, Btm, Btl, pbuf, k, k, k / dS[i]);
        if (i < 2)
            reduce_score_kernel<<<k / 2, 256, 0, stream>>>(pbuf, dS[i], k, p_w[i + 1],
                                                           xout[i], score, keys, rank);
        else
            reduce_kernel<<<(k * 128 / 4 + 255) / 256, 256, 0, stream>>>(pbuf, dS[i],
                                                                         (size_t)k * 128,
                                                                         nullptr, 1, xout[i]);
    }

    // ---------------- up path (bf16 MFMA) ----------------
    const float* res[3] = {x2, x1, feat};
    const float* graphs[3] = {Hg1, Hg0, H};
    const int* upos[3] = {pos1, pos0, nullptr};   // T-row permute matching graph's column order
    const int* usel[3] = {sel2, sel1, sel0};      // rank array for fused residual+scatter
    const int un[3] = {2048, 4096, 8192};
    const int uS[3] = {8, 8, 4};
    for (int i = 0; i < 3; i++) {
        int n = un[i];
        // T = (res + scatter(xc)) @ Wu + bu  (bf16, K=128, S=2; add+scatter fused in A-stage)
        dim3 g1(n / 64, 2);
        mfma_gemm1_add_kernel<<<g1, 256, 0, stream>>>(res[i], xc, usel[i],
                                                      Wut + i * 16384, pbuf, n, 128, 64);
        // fused: reduce(S=2)+bias+pos-permute+transpose+cvt -> ttb
        dim3 tg(n / 32, 4);
        reduce_transpose_cvt_kernel<<<tg, 256, 0, stream>>>(pbuf, 2, n, bu[i], upos[i], ttb, n);
        // dst = relu(graph' @ T')  (bf16, K=n)
        dim3 g2(n / 64, uS[i]);
        mfma_gemm1_kernel<<<g2, 256, 0, stream>>>(graphs[i], ttb, pbuf, n, n, n / uS[i]);
        float* dst = (i == 2) ? out : xc;
        reduce_kernel<<<(n * 128 / 4 + 255) / 256, 256, 0, stream>>>(pbuf, uS[i],
                                                                     (size_t)n * 128,
                                                                     nullptr, 1, dst);
    }
    (void)in_sizes; (void)n_in; (void)out_size; (void)ws_size;
}